// Round 1
// baseline (1793.142 us; speedup 1.0000x reference)
//
#include <hip/hip_runtime.h>
#include <math.h>

// ---------------------------------------------------------------------------
// TextureWarpingModule: B=2, CH=CC=256, H=W=64, DG=8, K=9, GN_GROUPS=32
// fp32 correctness-first baseline. All tensors NCHW fp32.
// ---------------------------------------------------------------------------

#define PLANE 4096  // 64*64

// ---- 1) antialiased bilinear 2x downsample: (2,256,128,128)->(2,256,64,64)
__global__ __launch_bounds__(256) void k_down(const float* __restrict__ pr,
                                              float* __restrict__ out) {
  int idx = blockIdx.x * 256 + threadIdx.x;  // 2*256*64*64 = 2097152
  int x = idx & 63, y = (idx >> 6) & 63, bc = idx >> 12;
  const float* p = pr + (size_t)bc * 16384;
  const float w4[4] = {0.125f, 0.375f, 0.375f, 0.125f};
  float wy[4], wx[4];
  int ry[4], rx[4];
  float sy = 0.f, sx = 0.f;
#pragma unroll
  for (int t = 0; t < 4; ++t) {
    int yy = 2 * y - 1 + t;
    bool vy = (yy >= 0) && (yy < 128);
    wy[t] = vy ? w4[t] : 0.f; ry[t] = vy ? yy : 0; sy += wy[t];
    int xx = 2 * x - 1 + t;
    bool vx = (xx >= 0) && (xx < 128);
    wx[t] = vx ? w4[t] : 0.f; rx[t] = vx ? xx : 0; sx += wx[t];
  }
  float acc = 0.f;
#pragma unroll
  for (int t = 0; t < 4; ++t) {
    const float* rowp = p + ry[t] * 128;
    acc += wy[t] * (wx[0] * rowp[rx[0]] + wx[1] * rowp[rx[1]] +
                    wx[2] * rowp[rx[2]] + wx[3] * rowp[rx[3]]);
  }
  out[idx] = acc / (sy * sx);
}

// ---- 2) generic 3x3 conv, pad 1. Block: 64 px (one row) x 4 co-quads.
// CPT = output channels per thread; CO tile per block = 4*CPT.
template <int CPT>
__global__ __launch_bounds__(256) void k_conv3x3(const float* __restrict__ in,
                                                 const float* __restrict__ w,
                                                 const float* __restrict__ bias,
                                                 float* __restrict__ out,
                                                 int CI, int CO) {
  const int tid = threadIdx.x;
  const int px = tid & 63;
  const int coq = tid >> 6;  // 0..3
  const int row = blockIdx.x;
  const int b = row >> 6;
  const int y = row & 63;
  const int cotile = blockIdx.y * (4 * CPT);
  const int cobase = cotile + coq * CPT;

  __shared__ float wl[4 * CPT * 288];  // CO_tile x 32ci x 9

  float acc[CPT];
#pragma unroll
  for (int j = 0; j < CPT; ++j) acc[j] = 0.f;

  const int nchunks = CI >> 5;
  for (int cc = 0; cc < nchunks; ++cc) {
    __syncthreads();
    const int tot = 4 * CPT * 288;
    for (int i = tid; i < tot; i += 256) {
      int coi = i / 288;
      int rest = i - coi * 288;
      wl[i] = w[(size_t)(cotile + coi) * (CI * 9) + cc * 288 + rest];
    }
    __syncthreads();
    for (int ci2 = 0; ci2 < 32; ++ci2) {
      const float* xp = in + (((size_t)b * CI + (cc << 5) + ci2) << 12);
      float r[9];
#pragma unroll
      for (int ky = 0; ky < 3; ++ky) {
        int yy = y + ky - 1;
        bool vy = (yy >= 0) && (yy < 64);
        const float* rp = xp + yy * 64;
        r[ky * 3 + 0] = (vy && px > 0) ? rp[px - 1] : 0.f;
        r[ky * 3 + 1] = vy ? rp[px] : 0.f;
        r[ky * 3 + 2] = (vy && px < 63) ? rp[px + 1] : 0.f;
      }
#pragma unroll
      for (int j = 0; j < CPT; ++j) {
        const float* wr = &wl[(coq * CPT + j) * 288 + ci2 * 9];
        float a = acc[j];
#pragma unroll
        for (int k = 0; k < 9; ++k) a += r[k] * wr[k];
        acc[j] = a;
      }
    }
  }
#pragma unroll
  for (int j = 0; j < CPT; ++j) {
    int co = cobase + j;
    out[(((size_t)b * CO + co) << 12) + (y << 6) + px] = acc[j] + bias[co];
  }
}

// ---- 3) 1x1 conv. CI=512 reads inA (first 256 ch) then inB; CI=256 reads inA.
__global__ __launch_bounds__(256) void k_conv1x1(const float* __restrict__ inA,
                                                 const float* __restrict__ inB,
                                                 const float* __restrict__ w,
                                                 const float* __restrict__ bias,
                                                 float* __restrict__ out,
                                                 int CI, int CO) {
  const int tid = threadIdx.x;
  const int px = tid & 63;
  const int coq = tid >> 6;
  const int row = blockIdx.x;
  const int b = row >> 6;
  const int y = row & 63;
  const int cobase = blockIdx.y * 32 + coq * 8;
  const int pxy = (y << 6) + px;

  float acc[8];
#pragma unroll
  for (int j = 0; j < 8; ++j) acc[j] = 0.f;

  for (int ci = 0; ci < CI; ++ci) {
    const float* src = (ci < 256) ? inA : inB;
    int cim = ci & 255;
    float v = src[(((size_t)b << 8) + cim) * 4096 + pxy];
#pragma unroll
    for (int j = 0; j < 8; ++j) acc[j] += v * w[(size_t)(cobase + j) * CI + ci];
  }
#pragma unroll
  for (int j = 0; j < 8; ++j) {
    int co = cobase + j;
    out[(((size_t)b * CO + co) << 12) + pxy] = acc[j] + bias[co];
  }
}

// ---- 4) GroupNorm(32 groups of 8 ch) + SiLU, optional out-of-place.
__global__ __launch_bounds__(256) void k_gn_silu(const float* __restrict__ in,
                                                 float* __restrict__ out,
                                                 const float* __restrict__ gamma,
                                                 const float* __restrict__ beta) {
  const int bg = blockIdx.x;  // 64
  const int b = bg >> 5;
  const int g = bg & 31;
  const size_t off = ((((size_t)b << 5) + g) << 3) * 4096;  // (b*256+g*8)*4096
  const float* base = in + off;
  float* obase = out + off;

  float s = 0.f, ss = 0.f;
  for (int i = threadIdx.x; i < 32768; i += 256) {
    float v = base[i];
    s += v;
    ss += v * v;
  }
#pragma unroll
  for (int o = 32; o; o >>= 1) {
    s += __shfl_down(s, o);
    ss += __shfl_down(ss, o);
  }
  __shared__ float rs[4], rss[4];
  __shared__ float smu, srstd;
  int wid = threadIdx.x >> 6, lane = threadIdx.x & 63;
  if (lane == 0) { rs[wid] = s; rss[wid] = ss; }
  __syncthreads();
  if (threadIdx.x == 0) {
    float S = rs[0] + rs[1] + rs[2] + rs[3];
    float SS = rss[0] + rss[1] + rss[2] + rss[3];
    float mu = S * (1.f / 32768.f);
    float var = SS * (1.f / 32768.f) - mu * mu;
    smu = mu;
    srstd = rsqrtf(var + 1e-6f);
  }
  __syncthreads();
  float mu = smu, rstd = srstd;
  for (int i = threadIdx.x; i < 32768; i += 256) {
    int c = (g << 3) + (i >> 12);
    float v = (base[i] - mu) * rstd * gamma[c] + beta[c];
    obase[i] = v / (1.f + expf(-v));
  }
}

// ---- 5) depthwise 7x7, pad 3
__global__ __launch_bounds__(256) void k_dw7(const float* __restrict__ in,
                                             const float* __restrict__ w,
                                             const float* __restrict__ bias,
                                             float* __restrict__ out) {
  int idx = blockIdx.x * 256 + threadIdx.x;  // 2097152
  int x = idx & 63, y = (idx >> 6) & 63;
  int c = (idx >> 12) & 255;
  const float* xp = in + ((size_t)(idx >> 12) << 12);
  const float* wp = w + c * 49;
  float a = 0.f;
#pragma unroll
  for (int ky = 0; ky < 7; ++ky) {
    int yy = y + ky - 3;
    if ((unsigned)yy >= 64u) continue;
    const float* rp = xp + yy * 64;
#pragma unroll
    for (int kx = 0; kx < 7; ++kx) {
      int xx = x + kx - 3;
      if ((unsigned)xx >= 64u) continue;
      a += rp[xx] * wp[ky * 7 + kx];
    }
  }
  out[idx] = a + bias[c];
}

// ---- 6) transpose w_dcn (256,2304) -> wt (2304,256)
__global__ __launch_bounds__(256) void k_wt(const float* __restrict__ w,
                                            float* __restrict__ wt) {
  int i = blockIdx.x * 256 + threadIdx.x;  // 589824
  int kk = i >> 8, co = i & 255;
  wt[i] = w[(size_t)co * 2304 + kk];
}

// ---- 7) deformable conv v2. Block = 32-px tile (half row), all 256 co.
// Per g: geometry (9k x 32px) -> bilinear sample (32c x 9k x 32px) into LDS
// -> fp32 GEMM: acc[4co][8px] per thread; wave covers 64 co (16 quads x 4 pxg).
__global__ __launch_bounds__(256) void k_dcn(const float* __restrict__ x,
                                             const float* __restrict__ o,
                                             const float* __restrict__ wt,
                                             const float* __restrict__ bias,
                                             float* __restrict__ out) {
  const int blk = blockIdx.x;  // 256
  const int b = blk >> 7;
  const int pix0 = (blk & 127) << 5;
  const int y = pix0 >> 6;
  const int xb = pix0 & 63;  // 0 or 32
  const int tid = threadIdx.x;
  const int lane = tid & 63;
  const int wv = tid >> 6;
  const int co0 = (wv << 6) + ((lane & 15) << 2);  // 4 contiguous co
  const int pxs = (lane >> 4) << 3;                // 8 px

  __shared__ float w00[288], w01[288], w10[288], w11[288];
  __shared__ int i00[288], i01[288], i10[288], i11[288];
  __shared__ __align__(16) float val[288][36];  // [kk=c*9+k][px], padded

  float acc[4][8];
#pragma unroll
  for (int j = 0; j < 4; ++j)
#pragma unroll
    for (int p = 0; p < 8; ++p) acc[j][p] = 0.f;

  for (int g = 0; g < 8; ++g) {
    __syncthreads();  // protect LDS reuse across g
    // geometry for (k, px)
    for (int it = tid; it < 288; it += 256) {
      int k = it >> 5, px = it & 31;
      int xx = xb + px;
      const size_t chb = ((size_t)b * 216) << 12;
      int pxy = (y << 6) + xx;
      float oy = o[chb + ((size_t)(18 * g + 2 * k) << 12) + pxy];
      float ox = o[chb + ((size_t)(18 * g + 2 * k + 1) << 12) + pxy];
      float mm = o[chb + ((size_t)(144 + 9 * g + k) << 12) + pxy];
      float m = 1.f / (1.f + expf(-mm));
      float py = (float)(y + (k / 3) - 1) + oy;
      float pxf = (float)(xx + (k % 3) - 1) + ox;
      float y0f = floorf(py), x0f = floorf(pxf);
      float wy1 = py - y0f, wx1 = pxf - x0f;
      int y0 = (int)y0f, xi0 = (int)x0f;
      int y1 = y0 + 1, xi1 = xi0 + 1;
      float vy0 = (y0 >= 0 && y0 < 64) ? 1.f : 0.f;
      float vy1 = (y1 >= 0 && y1 < 64) ? 1.f : 0.f;
      float vx0 = (xi0 >= 0 && xi0 < 64) ? 1.f : 0.f;
      float vx1 = (xi1 >= 0 && xi1 < 64) ? 1.f : 0.f;
      int y0c = min(max(y0, 0), 63), y1c = min(max(y1, 0), 63);
      int x0c = min(max(xi0, 0), 63), x1c = min(max(xi1, 0), 63);
      float wy0 = 1.f - wy1, wx0 = 1.f - wx1;
      w00[it] = wy0 * wx0 * m * vy0 * vx0;
      w01[it] = wy0 * wx1 * m * vy0 * vx1;
      w10[it] = wy1 * wx0 * m * vy1 * vx0;
      w11[it] = wy1 * wx1 * m * vy1 * vx1;
      i00[it] = (y0c << 6) + x0c;
      i01[it] = (y0c << 6) + x1c;
      i10[it] = (y1c << 6) + x0c;
      i11[it] = (y1c << 6) + x1c;
    }
    __syncthreads();
    // sampling: 32c x 288(k,px)
    const float* xg = x + ((((size_t)b << 8) + (g << 5)) << 12);
    for (int it = tid; it < 9216; it += 256) {
      int c = it / 288;
      int r = it - c * 288;
      int k = r >> 5, px = r & 31;
      const float* xp = xg + ((size_t)c << 12);
      float v = w00[r] * xp[i00[r]] + w01[r] * xp[i01[r]] +
                w10[r] * xp[i10[r]] + w11[r] * xp[i11[r]];
      val[c * 9 + k][px] = v;
    }
    __syncthreads();
    // GEMM over this g's 288 kk
    const float* wg = wt + (((size_t)g * 288) << 8);
    for (int kk = 0; kk < 288; ++kk) {
      const float4 wq = *reinterpret_cast<const float4*>(wg + (kk << 8) + co0);
      const float4 v0 = *reinterpret_cast<const float4*>(&val[kk][pxs]);
      const float4 v1 = *reinterpret_cast<const float4*>(&val[kk][pxs + 4]);
      float wj[4] = {wq.x, wq.y, wq.z, wq.w};
      float vv[8] = {v0.x, v0.y, v0.z, v0.w, v1.x, v1.y, v1.z, v1.w};
#pragma unroll
      for (int j = 0; j < 4; ++j)
#pragma unroll
        for (int p = 0; p < 8; ++p) acc[j][p] += wj[j] * vv[p];
    }
  }
  // epilogue
#pragma unroll
  for (int j = 0; j < 4; ++j) {
    int co = co0 + j;
    float bv = bias[co];
    float* op = out + ((((size_t)b << 8) + co) << 12) + (y << 6) + xb + pxs;
#pragma unroll
    for (int p = 0; p < 8; ++p) op[p] = acc[j][p] + bv;
  }
}

// ---------------------------------------------------------------------------
extern "C" void kernel_launch(void* const* d_in, const int* in_sizes, int n_in,
                              void* d_out, int out_size, void* d_ws,
                              size_t ws_size, hipStream_t stream) {
  const float* x_main = (const float*)d_in[0];
  const float* prior = (const float*)d_in[1];
  const float* w_ds = (const float*)d_in[2];
  const float* b_ds = (const float*)d_in[3];
  const float* w1 = (const float*)d_in[4];
  const float* b1 = (const float*)d_in[5];
  const float* g1 = (const float*)d_in[6];
  const float* bt1 = (const float*)d_in[7];
  const float* w_dw = (const float*)d_in[8];
  const float* b_dw = (const float*)d_in[9];
  const float* g2 = (const float*)d_in[10];
  const float* bt2 = (const float*)d_in[11];
  const float* w2 = (const float*)d_in[12];
  const float* b2 = (const float*)d_in[13];
  const float* w3 = (const float*)d_in[14];
  const float* b3 = (const float*)d_in[15];
  const float* g3 = (const float*)d_in[16];
  const float* bt3 = (const float*)d_in[17];
  const float* w_off = (const float*)d_in[18];
  const float* b_off = (const float*)d_in[19];
  const float* w_dcn = (const float*)d_in[20];
  const float* b_dcn = (const float*)d_in[21];

  float* out = (float*)d_out;
  float* warp = out;               // 2*256*4096
  float* offf = out + 2097152;     // offset_feat output

  float* bufA = (float*)d_ws;
  float* bufB = bufA + 2097152;
  float* bufO = bufB + 2097152;    // o: 2*216*4096 = 1769472
  float* wt = bufO + 1769472;      // 2304*256

  // pr0 = antialiased 2x downsample(prior)
  k_down<<<8192, 256, 0, stream>>>(prior, bufA);
  // pr = conv3x3(pr0, w_ds)
  k_conv3x3<4><<<dim3(128, 16), 256, 0, stream>>>(bufA, w_ds, b_ds, bufB, 256, 256);
  // t = conv1x1(concat(pr, x_main), w1)
  k_conv1x1<<<dim3(128, 8), 256, 0, stream>>>(bufB, x_main, w1, b1, bufA, 512, 256);
  // t = silu(gn1(t))
  k_gn_silu<<<64, 256, 0, stream>>>(bufA, bufA, g1, bt1);
  // t = dwconv7x7(t)
  k_dw7<<<8192, 256, 0, stream>>>(bufA, w_dw, b_dw, bufB);
  // t = silu(gn2(t))
  k_gn_silu<<<64, 256, 0, stream>>>(bufB, bufB, g2, bt2);
  // t = conv1x1(t, w2)
  k_conv1x1<<<dim3(128, 8), 256, 0, stream>>>(bufB, bufB, w2, b2, bufA, 256, 256);
  // t3 = conv3x3(t, w3)
  k_conv3x3<4><<<dim3(128, 16), 256, 0, stream>>>(bufA, w3, b3, bufB, 256, 256);
  // offset_feat = silu(gn3(t3)) -> second output
  k_gn_silu<<<64, 256, 0, stream>>>(bufB, offf, g3, bt3);
  // o = conv3x3(offset_feat, w_off) (216 out ch)
  k_conv3x3<2><<<dim3(128, 27), 256, 0, stream>>>(offf, w_off, b_off, bufO, 256, 216);
  // wt = w_dcn^T
  k_wt<<<2304, 256, 0, stream>>>(w_dcn, wt);
  // warp_feat = deform_conv(x_main, o, wt)
  k_dcn<<<256, 256, 0, stream>>>(x_main, bufO, wt, b_dcn, warp);
}

// Round 2
// 633.611 us; speedup vs baseline: 2.8300x; 2.8300x over previous
//
#include <hip/hip_runtime.h>
#include <math.h>

// ---------------------------------------------------------------------------
// TextureWarpingModule  B=2, CH=CC=256, H=W=64, DG=8, K=9, GN=32 groups
// Round 2: all 5 convs -> bf16 MFMA implicit GEMM (NHWC bf16 activations),
// GN+SiLU and depthwise 7x7 rewritten NHWC-bf16. DCN/downsample still fp32.
// ---------------------------------------------------------------------------

typedef __attribute__((ext_vector_type(8))) short short8;   // 8 bf16 = 4 VGPR
typedef __attribute__((ext_vector_type(4))) float f32x4;
typedef unsigned short ushort_t;
typedef unsigned int uint_t;

__device__ __forceinline__ ushort_t f2bf(float f) {
  uint_t u = __float_as_uint(f);
  return (ushort_t)((u + 0x7fffu + ((u >> 16) & 1u)) >> 16);  // RNE
}
__device__ __forceinline__ float bf2f(ushort_t h) {
  return __uint_as_float(((uint_t)h) << 16);
}
__device__ __forceinline__ uint_t pk2(float a, float b) {
  return (uint_t)f2bf(a) | ((uint_t)f2bf(b) << 16);
}

#define GLL(g, l) \
  __builtin_amdgcn_global_load_lds((const __attribute__((address_space(1))) void*)(const void*)(g), \
                                   (__attribute__((address_space(3))) void*)(void*)(l), 16, 0, 0)
#define WAITVM(n) __builtin_amdgcn_s_waitcnt(0x0F70 | (n))
#define CFENCE() asm volatile("" ::: "memory")

// ---- ws layout (bytes) -----------------------------------------------------
#define OFF_P1   0u            // padded NHWC bf16 2x66x66x256  (4,460,544 B)
#define OFF_Y1   4460544u      // NHWC bf16 2x64x64x256         (4,194,304 B)
#define OFF_Y2   8654848u      // NHWC bf16 2x64x64x256
#define OFF_O    12849152u     // prn(bf16 NHWC) / later bufO fp32 NCHW 216ch (7,077,888 B)
#define OFF_WDS  17043456u     // [9][256][256] bf16
#define OFF_W1   18223104u     // [1][256][512] bf16
#define OFF_W2   18485248u     // [1][256][256] bf16
#define OFF_W3   18616320u     // [9][256][256] bf16
#define OFF_X    19927040u     // xb (NHWC bf16) ; later Woff @+0, wtd @+1179648
#define OFF_WOFF 19927040u
#define OFF_WTD  21106688u
#define OFF_WDW  24121344u     // [49][256] f32 depthwise weights transposed

// ---------------------------------------------------------------------------
// 1) antialiased bilinear 2x downsample  (fp32 NCHW in -> bf16 NCHW out)
__global__ __launch_bounds__(256) void k_down(const float* __restrict__ pr,
                                              ushort_t* __restrict__ out) {
  int idx = blockIdx.x * 256 + threadIdx.x;  // 2*256*64*64
  int x = idx & 63, y = (idx >> 6) & 63, bc = idx >> 12;
  const float* p = pr + (size_t)bc * 16384;
  const float w4[4] = {0.125f, 0.375f, 0.375f, 0.125f};
  float wy[4], wx[4];
  int ry[4], rx[4];
  float sy = 0.f, sx = 0.f;
#pragma unroll
  for (int t = 0; t < 4; ++t) {
    int yy = 2 * y - 1 + t;
    bool vy = (yy >= 0) && (yy < 128);
    wy[t] = vy ? w4[t] : 0.f; ry[t] = vy ? yy : 0; sy += wy[t];
    int xx = 2 * x - 1 + t;
    bool vx = (xx >= 0) && (xx < 128);
    wx[t] = vx ? w4[t] : 0.f; rx[t] = vx ? xx : 0; sx += wx[t];
  }
  float acc = 0.f;
#pragma unroll
  for (int t = 0; t < 4; ++t) {
    const float* rowp = p + ry[t] * 128;
    acc += wy[t] * (wx[0] * rowp[rx[0]] + wx[1] * rowp[rx[1]] +
                    wx[2] * rowp[rx[2]] + wx[3] * rowp[rx[3]]);
  }
  out[idx] = f2bf(acc / (sy * sx));
}

// ---------------------------------------------------------------------------
// 2) NCHW -> NHWC transpose (+ optional 1px pad offset), bf16 out
template <typename SrcT>
__global__ __launch_bounds__(256) void k_tr(const SrcT* __restrict__ src,
                                            ushort_t* __restrict__ dst,
                                            int pad) {
  __shared__ SrcT tile[64][65];
  int bx = blockIdx.x;                // 2*64*4 = 512
  int c4 = bx & 3, y = (bx >> 2) & 63, b = bx >> 8;
  int tid = threadIdx.x;
  int x = tid & 63, cl = tid >> 6;
#pragma unroll
  for (int i = 0; i < 16; ++i) {
    int c = (c4 << 6) + cl + (i << 2);
    tile[cl + (i << 2)][x] = src[(((size_t)(b * 256 + c)) << 12) + (y << 6) + x];
  }
  __syncthreads();
  int W = 64 + 2 * pad;
  int c2 = tid & 63, xq = tid >> 6;
#pragma unroll
  for (int i = 0; i < 16; ++i) {
    int x2 = xq + (i << 2);
    SrcT v = tile[c2][x2];
    ushort_t o;
    if constexpr (sizeof(SrcT) == 4) o = f2bf((float)v); else o = (ushort_t)v;
    dst[((size_t)((b * W + y + pad) * W + x2 + pad)) * 256 + (c4 << 6) + c2] = o;
  }
}

// ---------------------------------------------------------------------------
// 3) weight prep: Wds/W1/W2/W3 (bf16 [tap][co][ci]) + WdwT (f32 [49][256])
__global__ __launch_bounds__(256) void k_wprep_all(
    const float* __restrict__ w_ds, const float* __restrict__ w1,
    const float* __restrict__ w2, const float* __restrict__ w3,
    const float* __restrict__ w_dw,
    ushort_t* __restrict__ Wds, ushort_t* __restrict__ W1,
    ushort_t* __restrict__ W2, ushort_t* __restrict__ W3,
    float* __restrict__ Wdw) {
  int i = blockIdx.x * 256 + threadIdx.x;  // 1,388,800
  if (i < 589824) {
    int tap = i >> 16, r = i & 65535, co = r >> 8, ci = r & 255;
    Wds[i] = f2bf(w_ds[((co << 8) + ci) * 9 + tap]);
  } else if (i < 720896) {
    int l = i - 589824;
    W1[l] = f2bf(w1[l]);
  } else if (i < 786432) {
    int l = i - 720896;
    W2[l] = f2bf(w2[l]);
  } else if (i < 1376256) {
    int l = i - 786432;
    int tap = l >> 16, r = l & 65535, co = r >> 8, ci = r & 255;
    W3[l] = f2bf(w3[((co << 8) + ci) * 9 + tap]);
  } else if (i < 1388800) {
    int l = i - 1376256;                 // 49*256
    int t = l >> 8, c = l & 255;
    Wdw[l] = w_dw[c * 49 + t];
  }
}

__global__ __launch_bounds__(256) void k_wprep_off(const float* __restrict__ w_off,
                                                   ushort_t* __restrict__ Wof) {
  int i = blockIdx.x * 256 + threadIdx.x;  // 589824
  int tap = i >> 16, r = i & 65535, co = r >> 8, ci = r & 255;
  Wof[i] = (co < 216) ? f2bf(w_off[((co << 8) + ci) * 9 + tap]) : (ushort_t)0;
}

// ---------------------------------------------------------------------------
// 4) MFMA implicit-GEMM conv.  D[co][px] = sum_{tap,ci} W[co][tap,ci]*X[px'][ci]
// Block: (b,y) row x 128-co tile.  4 waves, wave = 32 co x 64 px (Mf=2,Nf=4).
// LDS: 3 x (A 4KB + B 8KB) triple buffer, counted-vmcnt pipeline.
template <int NTAPS, int CI>
__global__ __launch_bounds__(256) void k_convmfma(
    const ushort_t* __restrict__ srcA, const ushort_t* __restrict__ srcB,
    const ushort_t* __restrict__ wtp, const float* __restrict__ bias,
    float* __restrict__ outF,          // NCHW fp32 (or null)
    ushort_t* __restrict__ outB,       // NHWC bf16 (or null)
    int CO_real, int inH, int inW, int outW, int outPad) {
  const int gx = blockIdx.x;
  const int b = gx >> 6, y = gx & 63;
  const int cobase = blockIdx.y << 7;
  const int tid = threadIdx.x;
  const int wv = tid >> 6, lane = tid & 63;

  __shared__ __align__(16) char lds[36864];

  f32x4 acc[2][4];
#pragma unroll
  for (int mi = 0; mi < 2; ++mi)
#pragma unroll
    for (int ni = 0; ni < 4; ++ni) acc[mi][ni] = (f32x4)0.f;

  const int sub = lane >> 2;                       // 0..15 rows per GLL
  const int oct = (lane & 3) ^ ((lane >> 3) & 3);  // source-swizzled ci-octet

  auto stage = [&](int s, int bufidx) {
    int tap, chunk;
    if constexpr (NTAPS == 9) { tap = s >> 3; chunk = s & 7; }
    else { tap = 0; chunk = s; }
    char* lb = lds + bufidx * 12288;
    // A (activation) : instr wv covers px 16*wv..16*wv+15
    {
      int px = (wv << 4) + sub;
      int srow, scol;
      if constexpr (NTAPS == 9) { srow = y + tap / 3; scol = tap % 3 + px; }
      else { srow = y; scol = px; }
      const ushort_t* sp = srcA;
      int cil = chunk << 5;
      if constexpr (CI == 512) {
        if (chunk >= 8) { sp = srcB; cil = (chunk & 7) << 5; }
      }
      const ushort_t* g = sp + ((size_t)((b * inH + srow) * inW + scol) * 256 + cil + (oct << 3));
      GLL(g, lb + (wv << 10));
    }
    // B (weights): instrs wv, wv+4 cover co_local 16j..16j+15
#pragma unroll
    for (int q = 0; q < 2; ++q) {
      int j = wv + (q << 2);
      int col = (j << 4) + sub;
      const ushort_t* g = wtp + ((size_t)(tap * 256 + cobase + col) * CI + (chunk << 5) + (oct << 3));
      GLL(g, lb + 4096 + (j << 10));
    }
  };

  const int NSTEP = NTAPS * (CI >> 5);
  stage(0, 0);
  stage(1, 1);

  const int r15 = lane & 15;
  const int xo = (((lane >> 4) ^ ((lane >> 1) & 3)) << 4);

  for (int s = 0; s < NSTEP; ++s) {
    if (s + 2 < NSTEP) stage(s + 2, (s + 2) % 3);
    if (s + 2 < NSTEP) WAITVM(6);
    else if (s + 1 < NSTEP) WAITVM(3);
    else WAITVM(0);
    CFENCE();
    __builtin_amdgcn_s_barrier();
    CFENCE();
    char* lb = lds + (s % 3) * 12288;
    short8 af[2];
#pragma unroll
    for (int mi = 0; mi < 2; ++mi)
      af[mi] = *(const short8*)(lb + 4096 + (((wv << 5) + (mi << 4) + r15) << 6) + xo);
#pragma unroll
    for (int ni = 0; ni < 4; ++ni) {
      short8 bfr = *(const short8*)(lb + (((ni << 4) + r15) << 6) + xo);
      acc[0][ni] = __builtin_amdgcn_mfma_f32_16x16x32_bf16(af[0], bfr, acc[0][ni], 0, 0, 0);
      acc[1][ni] = __builtin_amdgcn_mfma_f32_16x16x32_bf16(af[1], bfr, acc[1][ni], 0, 0, 0);
    }
    CFENCE();
    __builtin_amdgcn_s_barrier();
    CFENCE();
  }

  // epilogue: lane holds D[co4 + r][px], co4 = 4 consecutive co
  const int coq = (lane >> 4) << 2;
  const int outH = 64 + 2 * outPad;
#pragma unroll
  for (int mi = 0; mi < 2; ++mi) {
    int co4 = cobase + (wv << 5) + (mi << 4) + coq;
    if (co4 >= CO_real) continue;
    float4 bv = *(const float4*)(bias + co4);
#pragma unroll
    for (int ni = 0; ni < 4; ++ni) {
      int px = (ni << 4) + r15;
      f32x4 a = acc[mi][ni];
      if (outF) {
        size_t e = ((size_t)(b * CO_real + co4)) * 4096 + (y << 6) + px;
        outF[e] = a[0] + bv.x;
        outF[e + 4096] = a[1] + bv.y;
        outF[e + 8192] = a[2] + bv.z;
        outF[e + 12288] = a[3] + bv.w;
      }
      if (outB) {
        size_t e = ((size_t)((b * outH + y + outPad) * outW + px + outPad)) * 256 + co4;
        uint2 u;
        u.x = pk2(a[0] + bv.x, a[1] + bv.y);
        u.y = pk2(a[2] + bv.z, a[3] + bv.w);
        *(uint2*)(outB + e) = u;
      }
    }
  }
}

// ---------------------------------------------------------------------------
// 5) GroupNorm(32 groups x 8ch) + SiLU on NHWC bf16.
//    outN: NHWC bf16 (pad-able). outC: optional NCHW fp32 copy.
__global__ __launch_bounds__(256) void k_gn_nhwc(const ushort_t* __restrict__ in,
                                                 ushort_t* __restrict__ outN,
                                                 int outW, int outPad,
                                                 float* __restrict__ outC,
                                                 const float* __restrict__ gamma,
                                                 const float* __restrict__ beta) {
  int bg = blockIdx.x;  // 64
  int b = bg >> 5, g = bg & 31, c0 = g << 3;
  const ushort_t* base = in + ((size_t)b * 4096) * 256 + c0;
  int tid = threadIdx.x;

  float s = 0.f, ss = 0.f;
  for (int i = tid; i < 4096; i += 256) {
    uint4 u = *(const uint4*)(base + (size_t)i * 256);
    uint_t w[4] = {u.x, u.y, u.z, u.w};
#pragma unroll
    for (int q = 0; q < 4; ++q) {
      float f0 = __uint_as_float(w[q] << 16);
      float f1 = __uint_as_float(w[q] & 0xffff0000u);
      s += f0 + f1;
      ss += f0 * f0 + f1 * f1;
    }
  }
#pragma unroll
  for (int o = 32; o; o >>= 1) {
    s += __shfl_down(s, o);
    ss += __shfl_down(ss, o);
  }
  __shared__ float rs[4], rss[4], smv[2];
  int wid = tid >> 6;
  if ((tid & 63) == 0) { rs[wid] = s; rss[wid] = ss; }
  __syncthreads();
  if (tid == 0) {
    float S = rs[0] + rs[1] + rs[2] + rs[3];
    float SS = rss[0] + rss[1] + rss[2] + rss[3];
    float mu = S * (1.f / 32768.f);
    float var = SS * (1.f / 32768.f) - mu * mu;
    smv[0] = mu;
    smv[1] = rsqrtf(var + 1e-6f);
  }
  __syncthreads();
  float mu = smv[0], rstd = smv[1];
  float gm[8], bt[8];
#pragma unroll
  for (int j = 0; j < 8; ++j) { gm[j] = gamma[c0 + j]; bt[j] = beta[c0 + j]; }

  for (int i = tid; i < 4096; i += 256) {
    uint4 u = *(const uint4*)(base + (size_t)i * 256);
    uint_t w[4] = {u.x, u.y, u.z, u.w};
    float o8[8];
#pragma unroll
    for (int q = 0; q < 4; ++q) {
      float f0 = __uint_as_float(w[q] << 16);
      float f1 = __uint_as_float(w[q] & 0xffff0000u);
      float v0 = (f0 - mu) * rstd * gm[2 * q] + bt[2 * q];
      float v1 = (f1 - mu) * rstd * gm[2 * q + 1] + bt[2 * q + 1];
      o8[2 * q] = v0 / (1.f + expf(-v0));
      o8[2 * q + 1] = v1 / (1.f + expf(-v1));
    }
    int yy = i >> 6, xx = i & 63;
    size_t e = ((size_t)((b * (64 + 2 * outPad) + yy + outPad) * outW + xx + outPad)) * 256 + c0;
    uint4 o;
    o.x = pk2(o8[0], o8[1]); o.y = pk2(o8[2], o8[3]);
    o.z = pk2(o8[4], o8[5]); o.w = pk2(o8[6], o8[7]);
    *(uint4*)(outN + e) = o;
    if (outC) {
      size_t cb = (((size_t)b << 8) + c0) * 4096 + i;
#pragma unroll
      for (int j = 0; j < 8; ++j) outC[cb + (size_t)j * 4096] = o8[j];
    }
  }
}

// ---------------------------------------------------------------------------
// 6) depthwise 7x7 pad 3, NHWC bf16.  thread = 8 channels x 1 px.
__global__ __launch_bounds__(256) void k_dw7_nhwc(const ushort_t* __restrict__ in,
                                                  const float* __restrict__ wdwT,
                                                  const float* __restrict__ bias,
                                                  ushort_t* __restrict__ out) {
  int tid = threadIdx.x;
  int oct = tid & 31, pxl = tid >> 5;
  int pxg = blockIdx.x * 8 + pxl;  // 8192
  int b = pxg >> 12, rem = pxg & 4095, y = rem >> 6, x = rem & 63;
  float a[8];
  float4 b0 = *(const float4*)(bias + (oct << 3));
  float4 b1 = *(const float4*)(bias + (oct << 3) + 4);
  a[0] = b0.x; a[1] = b0.y; a[2] = b0.z; a[3] = b0.w;
  a[4] = b1.x; a[5] = b1.y; a[6] = b1.z; a[7] = b1.w;
#pragma unroll
  for (int ky = 0; ky < 7; ++ky) {
    int yy = y + ky - 3;
    if ((unsigned)yy >= 64u) continue;
#pragma unroll
    for (int kx = 0; kx < 7; ++kx) {
      int xx = x + kx - 3;
      if ((unsigned)xx >= 64u) continue;
      int t = ky * 7 + kx;
      uint4 u = *(const uint4*)(in + ((size_t)((b << 12) + (yy << 6) + xx)) * 256 + (oct << 3));
      float4 w0 = *(const float4*)(wdwT + (t << 8) + (oct << 3));
      float4 w1 = *(const float4*)(wdwT + (t << 8) + (oct << 3) + 4);
      uint_t ws[4] = {u.x, u.y, u.z, u.w};
      float f[8];
#pragma unroll
      for (int q = 0; q < 4; ++q) {
        f[2 * q] = __uint_as_float(ws[q] << 16);
        f[2 * q + 1] = __uint_as_float(ws[q] & 0xffff0000u);
      }
      a[0] += f[0] * w0.x; a[1] += f[1] * w0.y; a[2] += f[2] * w0.z; a[3] += f[3] * w0.w;
      a[4] += f[4] * w1.x; a[5] += f[5] * w1.y; a[6] += f[6] * w1.z; a[7] += f[7] * w1.w;
    }
  }
  uint4 o;
  o.x = pk2(a[0], a[1]); o.y = pk2(a[2], a[3]);
  o.z = pk2(a[4], a[5]); o.w = pk2(a[6], a[7]);
  *(uint4*)(out + ((size_t)pxg) * 256 + (oct << 3)) = o;
}

// ---------------------------------------------------------------------------
// 7) transpose w_dcn (256,2304) -> wt (2304,256) fp32  (unchanged)
__global__ __launch_bounds__(256) void k_wt(const float* __restrict__ w,
                                            float* __restrict__ wt) {
  int i = blockIdx.x * 256 + threadIdx.x;  // 589824
  int kk = i >> 8, co = i & 255;
  wt[i] = w[(size_t)co * 2304 + kk];
}

// ---------------------------------------------------------------------------
// 8) deformable conv v2 (unchanged fp32 version)
__global__ __launch_bounds__(256) void k_dcn(const float* __restrict__ x,
                                             const float* __restrict__ o,
                                             const float* __restrict__ wt,
                                             const float* __restrict__ bias,
                                             float* __restrict__ out) {
  const int blk = blockIdx.x;  // 256
  const int b = blk >> 7;
  const int pix0 = (blk & 127) << 5;
  const int y = pix0 >> 6;
  const int xb = pix0 & 63;
  const int tid = threadIdx.x;
  const int lane = tid & 63;
  const int wv = tid >> 6;
  const int co0 = (wv << 6) + ((lane & 15) << 2);
  const int pxs = (lane >> 4) << 3;

  __shared__ float w00[288], w01[288], w10[288], w11[288];
  __shared__ int i00[288], i01[288], i10[288], i11[288];
  __shared__ __align__(16) float val[288][36];

  float acc[4][8];
#pragma unroll
  for (int j = 0; j < 4; ++j)
#pragma unroll
    for (int p = 0; p < 8; ++p) acc[j][p] = 0.f;

  for (int g = 0; g < 8; ++g) {
    __syncthreads();
    for (int it = tid; it < 288; it += 256) {
      int k = it >> 5, px = it & 31;
      int xx = xb + px;
      const size_t chb = ((size_t)b * 216) << 12;
      int pxy = (y << 6) + xx;
      float oy = o[chb + ((size_t)(18 * g + 2 * k) << 12) + pxy];
      float ox = o[chb + ((size_t)(18 * g + 2 * k + 1) << 12) + pxy];
      float mm = o[chb + ((size_t)(144 + 9 * g + k) << 12) + pxy];
      float m = 1.f / (1.f + expf(-mm));
      float py = (float)(y + (k / 3) - 1) + oy;
      float pxf = (float)(xx + (k % 3) - 1) + ox;
      float y0f = floorf(py), x0f = floorf(pxf);
      float wy1 = py - y0f, wx1 = pxf - x0f;
      int y0 = (int)y0f, xi0 = (int)x0f;
      int y1 = y0 + 1, xi1 = xi0 + 1;
      float vy0 = (y0 >= 0 && y0 < 64) ? 1.f : 0.f;
      float vy1 = (y1 >= 0 && y1 < 64) ? 1.f : 0.f;
      float vx0 = (xi0 >= 0 && xi0 < 64) ? 1.f : 0.f;
      float vx1 = (xi1 >= 0 && xi1 < 64) ? 1.f : 0.f;
      int y0c = min(max(y0, 0), 63), y1c = min(max(y1, 0), 63);
      int x0c = min(max(xi0, 0), 63), x1c = min(max(xi1, 0), 63);
      float wy0 = 1.f - wy1, wx0 = 1.f - wx1;
      w00[it] = wy0 * wx0 * m * vy0 * vx0;
      w01[it] = wy0 * wx1 * m * vy0 * vx1;
      w10[it] = wy1 * wx0 * m * vy1 * vx0;
      w11[it] = wy1 * wx1 * m * vy1 * vx1;
      i00[it] = (y0c << 6) + x0c;
      i01[it] = (y0c << 6) + x1c;
      i10[it] = (y1c << 6) + x0c;
      i11[it] = (y1c << 6) + x1c;
    }
    __syncthreads();
    const float* xg = x + ((((size_t)b << 8) + (g << 5)) << 12);
    for (int it = tid; it < 9216; it += 256) {
      int c = it / 288;
      int r = it - c * 288;
      int k = r >> 5, px = r & 31;
      const float* xp = xg + ((size_t)c << 12);
      float v = w00[r] * xp[i00[r]] + w01[r] * xp[i01[r]] +
                w10[r] * xp[i10[r]] + w11[r] * xp[i11[r]];
      val[c * 9 + k][px] = v;
    }
    __syncthreads();
    const float* wg = wt + (((size_t)g * 288) << 8);
    for (int kk = 0; kk < 288; ++kk) {
      const float4 wq = *reinterpret_cast<const float4*>(wg + (kk << 8) + co0);
      const float4 v0 = *reinterpret_cast<const float4*>(&val[kk][pxs]);
      const float4 v1 = *reinterpret_cast<const float4*>(&val[kk][pxs + 4]);
      float wj[4] = {wq.x, wq.y, wq.z, wq.w};
      float vv[8] = {v0.x, v0.y, v0.z, v0.w, v1.x, v1.y, v1.z, v1.w};
#pragma unroll
      for (int j = 0; j < 4; ++j)
#pragma unroll
        for (int p = 0; p < 8; ++p) acc[j][p] += wj[j] * vv[p];
    }
  }
#pragma unroll
  for (int j = 0; j < 4; ++j) {
    int co = co0 + j;
    float bv = bias[co];
    float* op = out + ((((size_t)b << 8) + co) << 12) + (y << 6) + xb + pxs;
#pragma unroll
    for (int p = 0; p < 8; ++p) op[p] = acc[j][p] + bv;
  }
}

// ---------------------------------------------------------------------------
extern "C" void kernel_launch(void* const* d_in, const int* in_sizes, int n_in,
                              void* d_out, int out_size, void* d_ws,
                              size_t ws_size, hipStream_t stream) {
  const float* x_main = (const float*)d_in[0];
  const float* prior = (const float*)d_in[1];
  const float* w_ds = (const float*)d_in[2];
  const float* b_ds = (const float*)d_in[3];
  const float* w1 = (const float*)d_in[4];
  const float* b1 = (const float*)d_in[5];
  const float* g1 = (const float*)d_in[6];
  const float* bt1 = (const float*)d_in[7];
  const float* w_dw = (const float*)d_in[8];
  const float* b_dw = (const float*)d_in[9];
  const float* g2 = (const float*)d_in[10];
  const float* bt2 = (const float*)d_in[11];
  const float* w2 = (const float*)d_in[12];
  const float* b2 = (const float*)d_in[13];
  const float* w3 = (const float*)d_in[14];
  const float* b3 = (const float*)d_in[15];
  const float* g3 = (const float*)d_in[16];
  const float* bt3 = (const float*)d_in[17];
  const float* w_off = (const float*)d_in[18];
  const float* b_off = (const float*)d_in[19];
  const float* w_dcn = (const float*)d_in[20];
  const float* b_dcn = (const float*)d_in[21];

  float* out = (float*)d_out;
  float* warp = out;
  float* offf = out + 2097152;

  char* ws = (char*)d_ws;
  ushort_t* P1 = (ushort_t*)(ws + OFF_P1);
  ushort_t* Y1 = (ushort_t*)(ws + OFF_Y1);
  ushort_t* Y2 = (ushort_t*)(ws + OFF_Y2);
  ushort_t* prn = (ushort_t*)(ws + OFF_O);
  float* bufO = (float*)(ws + OFF_O);
  ushort_t* Wds = (ushort_t*)(ws + OFF_WDS);
  ushort_t* W1 = (ushort_t*)(ws + OFF_W1);
  ushort_t* W2 = (ushort_t*)(ws + OFF_W2);
  ushort_t* W3 = (ushort_t*)(ws + OFF_W3);
  ushort_t* xb = (ushort_t*)(ws + OFF_X);
  ushort_t* Wof = (ushort_t*)(ws + OFF_WOFF);
  float* wtd = (float*)(ws + OFF_WTD);
  float* Wdw = (float*)(ws + OFF_WDW);

  // pad buffer zero (P1 pads must be 0; interiors overwritten later)
  hipMemsetAsync(ws + OFF_P1, 0, 4460544, stream);
  // weight prep
  k_wprep_all<<<5425, 256, 0, stream>>>(w_ds, w1, w2, w3, w_dw, Wds, W1, W2, W3, Wdw);
  // downsample prior -> Y2 (bf16 NCHW temp), then into padded NHWC P1
  k_down<<<8192, 256, 0, stream>>>(prior, Y2);
  k_tr<ushort_t><<<512, 256, 0, stream>>>(Y2, P1, 1);
  // x_main -> xb (NHWC bf16)
  k_tr<float><<<512, 256, 0, stream>>>(x_main, xb, 0);
  // conv3x3 w_ds : P1 -> prn (NHWC bf16)
  k_convmfma<9, 256><<<dim3(128, 2), 256, 0, stream>>>(P1, nullptr, Wds, b_ds,
                                                       nullptr, prn, 256, 66, 66, 64, 0);
  // conv1x1 w1 : concat(prn, xb) -> Y1 (NHWC bf16)
  k_convmfma<1, 512><<<dim3(128, 2), 256, 0, stream>>>(prn, xb, W1, b1,
                                                       nullptr, Y1, 256, 64, 64, 64, 0);
  // gn1+silu : Y1 -> Y2
  k_gn_nhwc<<<64, 256, 0, stream>>>(Y1, Y2, 64, 0, nullptr, g1, bt1);
  // w_off prep (after xb is dead; shares region)
  k_wprep_off<<<2304, 256, 0, stream>>>(w_off, Wof);
  // dw7 : Y2 -> Y1
  k_dw7_nhwc<<<1024, 256, 0, stream>>>(Y2, Wdw, b_dw, Y1);
  // gn2+silu : Y1 -> Y2
  k_gn_nhwc<<<64, 256, 0, stream>>>(Y1, Y2, 64, 0, nullptr, g2, bt2);
  // conv1x1 w2 : Y2 -> P1 (padded NHWC)
  k_convmfma<1, 256><<<dim3(128, 2), 256, 0, stream>>>(Y2, nullptr, W2, b2,
                                                       nullptr, P1, 256, 64, 64, 66, 1);
  // conv3x3 w3 : P1 -> Y1 (NHWC bf16)
  k_convmfma<9, 256><<<dim3(128, 2), 256, 0, stream>>>(P1, nullptr, W3, b3,
                                                       nullptr, Y1, 256, 66, 66, 64, 0);
  // gn3+silu : Y1 -> (offset_feat fp32 NCHW out) + P1 (padded NHWC)
  k_gn_nhwc<<<64, 256, 0, stream>>>(Y1, P1, 66, 1, offf, g3, bt3);
  // conv3x3 w_off : P1 -> bufO (fp32 NCHW, 216 ch)
  k_convmfma<9, 256><<<dim3(128, 2), 256, 0, stream>>>(P1, nullptr, Wof, b_off,
                                                       bufO, nullptr, 216, 66, 66, 64, 0);
  // dcn weights + deformable conv (fp32)
  k_wt<<<2304, 256, 0, stream>>>(w_dcn, wtd);
  k_dcn<<<256, 256, 0, stream>>>(x_main, bufO, wtd, b_dcn, warp);
}

// Round 3
// 419.154 us; speedup vs baseline: 4.2780x; 1.5116x over previous
//
#include <hip/hip_runtime.h>
#include <math.h>

// ---------------------------------------------------------------------------
// TextureWarpingModule  B=2, CH=CC=256, H=W=64, DG=8, K=9, GN=32 groups
// Round 3: DCN -> bf16 MFMA (sample into LDS k-major, ds_write_b128,
// canonical fragments). o-buffer bf16 NCHW. Convs unchanged from round 2.
// ---------------------------------------------------------------------------

typedef __attribute__((ext_vector_type(8))) short short8;   // 8 bf16 = 4 VGPR
typedef __attribute__((ext_vector_type(4))) float f32x4;
typedef unsigned short ushort_t;
typedef unsigned int uint_t;

__device__ __forceinline__ ushort_t f2bf(float f) {
  uint_t u = __float_as_uint(f);
  return (ushort_t)((u + 0x7fffu + ((u >> 16) & 1u)) >> 16);  // RNE
}
__device__ __forceinline__ float bf2f(ushort_t h) {
  return __uint_as_float(((uint_t)h) << 16);
}
__device__ __forceinline__ uint_t pk2(float a, float b) {
  return (uint_t)f2bf(a) | ((uint_t)f2bf(b) << 16);
}

#define GLL(g, l) \
  __builtin_amdgcn_global_load_lds((const __attribute__((address_space(1))) void*)(const void*)(g), \
                                   (__attribute__((address_space(3))) void*)(void*)(l), 16, 0, 0)
#define WAITVM(n) __builtin_amdgcn_s_waitcnt(0x0F70 | (n))
#define CFENCE() asm volatile("" ::: "memory")

// ---- ws layout (bytes) -----------------------------------------------------
#define OFF_P1   0u            // padded NHWC bf16 2x66x66x256  (4,460,544)
#define OFF_Y1   4460544u      // NHWC bf16 2x64x64x256 (4,194,304); later Wof/Wd
#define OFF_Y2   8654848u      // NHWC bf16 2x64x64x256 (also bf16-NCHW temp)
#define OFF_O    12849152u     // o bf16 NCHW 2x216x4096 (3,538,944)
#define OFF_WDS  16388096u     // [9][256][256] bf16
#define OFF_W1   17567744u     // [1][256][512] bf16
#define OFF_W2   17829888u     // [1][256][256] bf16
#define OFF_W3   17960960u     // [9][256][256] bf16
#define OFF_X    19140608u     // xb NHWC bf16 (4,194,304) — live until DCN
#define OFF_WDW  23334912u     // [49][256] f32
// end: 23,385,088  (< 26.2MB proven)

// ---------------------------------------------------------------------------
// 1) antialiased bilinear 2x downsample  (fp32 NCHW in -> bf16 NCHW out)
__global__ __launch_bounds__(256) void k_down(const float* __restrict__ pr,
                                              ushort_t* __restrict__ out) {
  int idx = blockIdx.x * 256 + threadIdx.x;  // 2*256*64*64
  int x = idx & 63, y = (idx >> 6) & 63, bc = idx >> 12;
  const float* p = pr + (size_t)bc * 16384;
  const float w4[4] = {0.125f, 0.375f, 0.375f, 0.125f};
  float wy[4], wx[4];
  int ry[4], rx[4];
  float sy = 0.f, sx = 0.f;
#pragma unroll
  for (int t = 0; t < 4; ++t) {
    int yy = 2 * y - 1 + t;
    bool vy = (yy >= 0) && (yy < 128);
    wy[t] = vy ? w4[t] : 0.f; ry[t] = vy ? yy : 0; sy += wy[t];
    int xx = 2 * x - 1 + t;
    bool vx = (xx >= 0) && (xx < 128);
    wx[t] = vx ? w4[t] : 0.f; rx[t] = vx ? xx : 0; sx += wx[t];
  }
  float acc = 0.f;
#pragma unroll
  for (int t = 0; t < 4; ++t) {
    const float* rowp = p + ry[t] * 128;
    acc += wy[t] * (wx[0] * rowp[rx[0]] + wx[1] * rowp[rx[1]] +
                    wx[2] * rowp[rx[2]] + wx[3] * rowp[rx[3]]);
  }
  out[idx] = f2bf(acc / (sy * sx));
}

// ---------------------------------------------------------------------------
// 2) NCHW -> NHWC transpose (+ optional 1px pad offset), bf16 out
template <typename SrcT>
__global__ __launch_bounds__(256) void k_tr(const SrcT* __restrict__ src,
                                            ushort_t* __restrict__ dst,
                                            int pad) {
  __shared__ SrcT tile[64][65];
  int bx = blockIdx.x;                // 2*64*4 = 512
  int c4 = bx & 3, y = (bx >> 2) & 63, b = bx >> 8;
  int tid = threadIdx.x;
  int x = tid & 63, cl = tid >> 6;
#pragma unroll
  for (int i = 0; i < 16; ++i) {
    int c = (c4 << 6) + cl + (i << 2);
    tile[cl + (i << 2)][x] = src[(((size_t)(b * 256 + c)) << 12) + (y << 6) + x];
  }
  __syncthreads();
  int W = 64 + 2 * pad;
  int c2 = tid & 63, xq = tid >> 6;
#pragma unroll
  for (int i = 0; i < 16; ++i) {
    int x2 = xq + (i << 2);
    SrcT v = tile[c2][x2];
    ushort_t o;
    if constexpr (sizeof(SrcT) == 4) o = f2bf((float)v); else o = (ushort_t)v;
    dst[((size_t)((b * W + y + pad) * W + x2 + pad)) * 256 + (c4 << 6) + c2] = o;
  }
}

// ---------------------------------------------------------------------------
// 3) weight prep: Wds/W1/W2/W3 (bf16 [tap][co][ci]) + WdwT (f32 [49][256])
__global__ __launch_bounds__(256) void k_wprep_all(
    const float* __restrict__ w_ds, const float* __restrict__ w1,
    const float* __restrict__ w2, const float* __restrict__ w3,
    const float* __restrict__ w_dw,
    ushort_t* __restrict__ Wds, ushort_t* __restrict__ W1,
    ushort_t* __restrict__ W2, ushort_t* __restrict__ W3,
    float* __restrict__ Wdw) {
  int i = blockIdx.x * 256 + threadIdx.x;  // 1,388,800
  if (i < 589824) {
    int tap = i >> 16, r = i & 65535, co = r >> 8, ci = r & 255;
    Wds[i] = f2bf(w_ds[((co << 8) + ci) * 9 + tap]);
  } else if (i < 720896) {
    int l = i - 589824;
    W1[l] = f2bf(w1[l]);
  } else if (i < 786432) {
    int l = i - 720896;
    W2[l] = f2bf(w2[l]);
  } else if (i < 1376256) {
    int l = i - 786432;
    int tap = l >> 16, r = l & 65535, co = r >> 8, ci = r & 255;
    W3[l] = f2bf(w3[((co << 8) + ci) * 9 + tap]);
  } else if (i < 1388800) {
    int l = i - 1376256;                 // 49*256
    int t = l >> 8, c = l & 255;
    Wdw[l] = w_dw[c * 49 + t];
  }
}

__global__ __launch_bounds__(256) void k_wprep_off(const float* __restrict__ w_off,
                                                   ushort_t* __restrict__ Wof) {
  int i = blockIdx.x * 256 + threadIdx.x;  // 589824
  int tap = i >> 16, r = i & 65535, co = r >> 8, ci = r & 255;
  Wof[i] = (co < 216) ? f2bf(w_off[((co << 8) + ci) * 9 + tap]) : (ushort_t)0;
}

// DCN weights: Wd[g][co][kk = k*32 + c] bf16 from w_dcn[co][ci=g*32+c][k]
__global__ __launch_bounds__(256) void k_wdcn(const float* __restrict__ w,
                                              ushort_t* __restrict__ Wd) {
  int i = blockIdx.x * 256 + threadIdx.x;  // 589824
  int kk = i % 288;
  int rest = i / 288;
  int co = rest & 255, g = rest >> 8;
  int k = kk >> 5, c = kk & 31;
  Wd[i] = f2bf(w[(size_t)co * 2304 + (g * 32 + c) * 9 + k]);
}

// ---------------------------------------------------------------------------
// 4) MFMA implicit-GEMM conv.
template <int NTAPS, int CI>
__global__ __launch_bounds__(256) void k_convmfma(
    const ushort_t* __restrict__ srcA, const ushort_t* __restrict__ srcB,
    const ushort_t* __restrict__ wtp, const float* __restrict__ bias,
    float* __restrict__ outF,          // NCHW fp32 (or null)
    ushort_t* __restrict__ outB,       // NHWC bf16 (or null)
    ushort_t* __restrict__ outC16,     // NCHW bf16 (or null)
    int CO_real, int inH, int inW, int outW, int outPad) {
  const int gx = blockIdx.x;
  const int b = gx >> 6, y = gx & 63;
  const int cobase = blockIdx.y << 7;
  const int tid = threadIdx.x;
  const int wv = tid >> 6, lane = tid & 63;

  __shared__ __align__(16) char lds[36864];

  f32x4 acc[2][4];
#pragma unroll
  for (int mi = 0; mi < 2; ++mi)
#pragma unroll
    for (int ni = 0; ni < 4; ++ni) acc[mi][ni] = (f32x4)0.f;

  const int sub = lane >> 2;                       // 0..15 rows per GLL
  const int oct = (lane & 3) ^ ((lane >> 3) & 3);  // source-swizzled ci-octet

  auto stage = [&](int s, int bufidx) {
    int tap, chunk;
    if constexpr (NTAPS == 9) { tap = s >> 3; chunk = s & 7; }
    else { tap = 0; chunk = s; }
    char* lb = lds + bufidx * 12288;
    {
      int px = (wv << 4) + sub;
      int srow, scol;
      if constexpr (NTAPS == 9) { srow = y + tap / 3; scol = tap % 3 + px; }
      else { srow = y; scol = px; }
      const ushort_t* sp = srcA;
      int cil = chunk << 5;
      if constexpr (CI == 512) {
        if (chunk >= 8) { sp = srcB; cil = (chunk & 7) << 5; }
      }
      const ushort_t* g = sp + ((size_t)((b * inH + srow) * inW + scol) * 256 + cil + (oct << 3));
      GLL(g, lb + (wv << 10));
    }
#pragma unroll
    for (int q = 0; q < 2; ++q) {
      int j = wv + (q << 2);
      int col = (j << 4) + sub;
      const ushort_t* g = wtp + ((size_t)(tap * 256 + cobase + col) * CI + (chunk << 5) + (oct << 3));
      GLL(g, lb + 4096 + (j << 10));
    }
  };

  const int NSTEP = NTAPS * (CI >> 5);
  stage(0, 0);
  stage(1, 1);

  const int r15 = lane & 15;
  const int xo = (((lane >> 4) ^ ((lane >> 1) & 3)) << 4);

  for (int s = 0; s < NSTEP; ++s) {
    if (s + 2 < NSTEP) stage(s + 2, (s + 2) % 3);
    if (s + 2 < NSTEP) WAITVM(6);
    else if (s + 1 < NSTEP) WAITVM(3);
    else WAITVM(0);
    CFENCE();
    __builtin_amdgcn_s_barrier();
    CFENCE();
    char* lb = lds + (s % 3) * 12288;
    short8 af[2];
#pragma unroll
    for (int mi = 0; mi < 2; ++mi)
      af[mi] = *(const short8*)(lb + 4096 + (((wv << 5) + (mi << 4) + r15) << 6) + xo);
#pragma unroll
    for (int ni = 0; ni < 4; ++ni) {
      short8 bfr = *(const short8*)(lb + (((ni << 4) + r15) << 6) + xo);
      acc[0][ni] = __builtin_amdgcn_mfma_f32_16x16x32_bf16(af[0], bfr, acc[0][ni], 0, 0, 0);
      acc[1][ni] = __builtin_amdgcn_mfma_f32_16x16x32_bf16(af[1], bfr, acc[1][ni], 0, 0, 0);
    }
    CFENCE();
    __builtin_amdgcn_s_barrier();
    CFENCE();
  }

  const int coq = (lane >> 4) << 2;
  const int outH = 64 + 2 * outPad;
#pragma unroll
  for (int mi = 0; mi < 2; ++mi) {
    int co4 = cobase + (wv << 5) + (mi << 4) + coq;
    if (co4 >= CO_real) continue;
    float4 bv = *(const float4*)(bias + co4);
#pragma unroll
    for (int ni = 0; ni < 4; ++ni) {
      int px = (ni << 4) + r15;
      f32x4 a = acc[mi][ni];
      if (outF) {
        size_t e = ((size_t)(b * CO_real + co4)) * 4096 + (y << 6) + px;
        outF[e] = a[0] + bv.x;
        outF[e + 4096] = a[1] + bv.y;
        outF[e + 8192] = a[2] + bv.z;
        outF[e + 12288] = a[3] + bv.w;
      }
      if (outC16) {
        size_t e = ((size_t)(b * CO_real + co4)) * 4096 + (y << 6) + px;
        outC16[e] = f2bf(a[0] + bv.x);
        outC16[e + 4096] = f2bf(a[1] + bv.y);
        outC16[e + 8192] = f2bf(a[2] + bv.z);
        outC16[e + 12288] = f2bf(a[3] + bv.w);
      }
      if (outB) {
        size_t e = ((size_t)((b * outH + y + outPad) * outW + px + outPad)) * 256 + co4;
        uint2 u;
        u.x = pk2(a[0] + bv.x, a[1] + bv.y);
        u.y = pk2(a[2] + bv.z, a[3] + bv.w);
        *(uint2*)(outB + e) = u;
      }
    }
  }
}

// ---------------------------------------------------------------------------
// 5) GroupNorm + SiLU on NHWC bf16.
__global__ __launch_bounds__(256) void k_gn_nhwc(const ushort_t* __restrict__ in,
                                                 ushort_t* __restrict__ outN,
                                                 int outW, int outPad,
                                                 float* __restrict__ outC,
                                                 const float* __restrict__ gamma,
                                                 const float* __restrict__ beta) {
  int bg = blockIdx.x;  // 64
  int b = bg >> 5, g = bg & 31, c0 = g << 3;
  const ushort_t* base = in + ((size_t)b * 4096) * 256 + c0;
  int tid = threadIdx.x;

  float s = 0.f, ss = 0.f;
  for (int i = tid; i < 4096; i += 256) {
    uint4 u = *(const uint4*)(base + (size_t)i * 256);
    uint_t w[4] = {u.x, u.y, u.z, u.w};
#pragma unroll
    for (int q = 0; q < 4; ++q) {
      float f0 = __uint_as_float(w[q] << 16);
      float f1 = __uint_as_float(w[q] & 0xffff0000u);
      s += f0 + f1;
      ss += f0 * f0 + f1 * f1;
    }
  }
#pragma unroll
  for (int o = 32; o; o >>= 1) {
    s += __shfl_down(s, o);
    ss += __shfl_down(ss, o);
  }
  __shared__ float rs[4], rss[4], smv[2];
  int wid = tid >> 6;
  if ((tid & 63) == 0) { rs[wid] = s; rss[wid] = ss; }
  __syncthreads();
  if (tid == 0) {
    float S = rs[0] + rs[1] + rs[2] + rs[3];
    float SS = rss[0] + rss[1] + rss[2] + rss[3];
    float mu = S * (1.f / 32768.f);
    float var = SS * (1.f / 32768.f) - mu * mu;
    smv[0] = mu;
    smv[1] = rsqrtf(var + 1e-6f);
  }
  __syncthreads();
  float mu = smv[0], rstd = smv[1];
  float gm[8], bt[8];
#pragma unroll
  for (int j = 0; j < 8; ++j) { gm[j] = gamma[c0 + j]; bt[j] = beta[c0 + j]; }

  for (int i = tid; i < 4096; i += 256) {
    uint4 u = *(const uint4*)(base + (size_t)i * 256);
    uint_t w[4] = {u.x, u.y, u.z, u.w};
    float o8[8];
#pragma unroll
    for (int q = 0; q < 4; ++q) {
      float f0 = __uint_as_float(w[q] << 16);
      float f1 = __uint_as_float(w[q] & 0xffff0000u);
      float v0 = (f0 - mu) * rstd * gm[2 * q] + bt[2 * q];
      float v1 = (f1 - mu) * rstd * gm[2 * q + 1] + bt[2 * q + 1];
      o8[2 * q] = v0 / (1.f + expf(-v0));
      o8[2 * q + 1] = v1 / (1.f + expf(-v1));
    }
    int yy = i >> 6, xx = i & 63;
    size_t e = ((size_t)((b * (64 + 2 * outPad) + yy + outPad) * outW + xx + outPad)) * 256 + c0;
    uint4 o;
    o.x = pk2(o8[0], o8[1]); o.y = pk2(o8[2], o8[3]);
    o.z = pk2(o8[4], o8[5]); o.w = pk2(o8[6], o8[7]);
    *(uint4*)(outN + e) = o;
    if (outC) {
      size_t cb = (((size_t)b << 8) + c0) * 4096 + i;
#pragma unroll
      for (int j = 0; j < 8; ++j) outC[cb + (size_t)j * 4096] = o8[j];
    }
  }
}

// ---------------------------------------------------------------------------
// 6) depthwise 7x7 pad 3, NHWC bf16.
__global__ __launch_bounds__(256) void k_dw7_nhwc(const ushort_t* __restrict__ in,
                                                  const float* __restrict__ wdwT,
                                                  const float* __restrict__ bias,
                                                  ushort_t* __restrict__ out) {
  int tid = threadIdx.x;
  int oct = tid & 31, pxl = tid >> 5;
  int pxg = blockIdx.x * 8 + pxl;  // 8192
  int b = pxg >> 12, rem = pxg & 4095, y = rem >> 6, x = rem & 63;
  float a[8];
  float4 b0 = *(const float4*)(bias + (oct << 3));
  float4 b1 = *(const float4*)(bias + (oct << 3) + 4);
  a[0] = b0.x; a[1] = b0.y; a[2] = b0.z; a[3] = b0.w;
  a[4] = b1.x; a[5] = b1.y; a[6] = b1.z; a[7] = b1.w;
#pragma unroll
  for (int ky = 0; ky < 7; ++ky) {
    int yy = y + ky - 3;
    if ((unsigned)yy >= 64u) continue;
#pragma unroll
    for (int kx = 0; kx < 7; ++kx) {
      int xx = x + kx - 3;
      if ((unsigned)xx >= 64u) continue;
      int t = ky * 7 + kx;
      uint4 u = *(const uint4*)(in + ((size_t)((b << 12) + (yy << 6) + xx)) * 256 + (oct << 3));
      float4 w0 = *(const float4*)(wdwT + (t << 8) + (oct << 3));
      float4 w1 = *(const float4*)(wdwT + (t << 8) + (oct << 3) + 4);
      uint_t ws[4] = {u.x, u.y, u.z, u.w};
      float f[8];
#pragma unroll
      for (int q = 0; q < 4; ++q) {
        f[2 * q] = __uint_as_float(ws[q] << 16);
        f[2 * q + 1] = __uint_as_float(ws[q] & 0xffff0000u);
      }
      a[0] += f[0] * w0.x; a[1] += f[1] * w0.y; a[2] += f[2] * w0.z; a[3] += f[3] * w0.w;
      a[4] += f[4] * w1.x; a[5] += f[5] * w1.y; a[6] += f[6] * w1.z; a[7] += f[7] * w1.w;
    }
  }
  uint4 o;
  o.x = pk2(a[0], a[1]); o.y = pk2(a[2], a[3]);
  o.z = pk2(a[4], a[5]); o.w = pk2(a[6], a[7]);
  *(uint4*)(out + ((size_t)pxg) * 256 + (oct << 3)) = o;
}

// ---------------------------------------------------------------------------
// 7) deformable conv v2, bf16 MFMA.
// Block = (b,y) row x 128-co half. 4 waves: wave = 32co x 64px, acc[2][4].
// Per g: geometry -> sample (k-major val, ds_write_b128) -> MFMA GEMM (K=288).
__global__ __launch_bounds__(256) void k_dcn_mfma(
    const ushort_t* __restrict__ xb,   // NHWC bf16 [2][64][64][256]
    const ushort_t* __restrict__ o16,  // NCHW bf16 [2][216][4096]
    const ushort_t* __restrict__ Wd,   // [8][256][288] bf16, kk=k*32+c
    const float* __restrict__ bias,
    float* __restrict__ out) {         // NCHW fp32 [2][256][4096]
  const int gx = blockIdx.x;           // 128 = b*64+y
  const int b = gx >> 6, y = gx & 63;
  const int cobase = blockIdx.y << 7;
  const int tid = threadIdx.x;
  const int wv = tid >> 6, lane = tid & 63;
  const int r15 = lane & 15, oct = lane >> 4;

  __shared__ float gw[4][576];
  __shared__ int gi[4][576];
  __shared__ __align__(16) ushort_t val[64][296];  // row stride 592B

  f32x4 acc[2][4];
#pragma unroll
  for (int mi = 0; mi < 2; ++mi)
#pragma unroll
    for (int ni = 0; ni < 4; ++ni) acc[mi][ni] = (f32x4)0.f;

  const int spx = tid & 63, sc8 = tid >> 6;  // sampling assignment
  const size_t obase = (size_t)b * 216 * 4096;

  for (int g = 0; g < 8; ++g) {
    __syncthreads();
    // ---- geometry: (k, px) for this row
    for (int t = tid; t < 576; t += 256) {
      int k = t >> 6, px = t & 63;
      int pxy = (y << 6) + px;
      float oy = bf2f(o16[obase + (size_t)(18 * g + 2 * k) * 4096 + pxy]);
      float ox = bf2f(o16[obase + (size_t)(18 * g + 2 * k + 1) * 4096 + pxy]);
      float mm = bf2f(o16[obase + (size_t)(144 + 9 * g + k) * 4096 + pxy]);
      float m = 1.f / (1.f + expf(-mm));
      float py = (float)(y + (k / 3) - 1) + oy;
      float pxf = (float)(px + (k % 3) - 1) + ox;
      float y0f = floorf(py), x0f = floorf(pxf);
      float wy1 = py - y0f, wx1 = pxf - x0f;
      int y0 = (int)y0f, xi0 = (int)x0f;
      int y1 = y0 + 1, xi1 = xi0 + 1;
      float vy0 = (y0 >= 0 && y0 < 64) ? 1.f : 0.f;
      float vy1 = (y1 >= 0 && y1 < 64) ? 1.f : 0.f;
      float vx0 = (xi0 >= 0 && xi0 < 64) ? 1.f : 0.f;
      float vx1 = (xi1 >= 0 && xi1 < 64) ? 1.f : 0.f;
      int y0c = min(max(y0, 0), 63), y1c = min(max(y1, 0), 63);
      int x0c = min(max(xi0, 0), 63), x1c = min(max(xi1, 0), 63);
      float wy0 = 1.f - wy1, wx0 = 1.f - wx1;
      gw[0][t] = wy0 * wx0 * m * vy0 * vx0;
      gw[1][t] = wy0 * wx1 * m * vy0 * vx1;
      gw[2][t] = wy1 * wx0 * m * vy1 * vx0;
      gw[3][t] = wy1 * wx1 * m * vy1 * vx1;
      gi[0][t] = (y0c << 6) + x0c;
      gi[1][t] = (y0c << 6) + x1c;
      gi[2][t] = (y1c << 6) + x0c;
      gi[3][t] = (y1c << 6) + x1c;
    }
    __syncthreads();
    // ---- sampling: thread = (px, c-octet); 9 taps, one b128 write each
    {
      const ushort_t* xg = xb + (((size_t)b << 12) * 256) + (g << 5) + (sc8 << 3);
#pragma unroll
      for (int k = 0; k < 9; ++k) {
        int t = (k << 6) + spx;
        float av[8];
#pragma unroll
        for (int j = 0; j < 8; ++j) av[j] = 0.f;
#pragma unroll
        for (int c4 = 0; c4 < 4; ++c4) {
          float wgt = gw[c4][t];
          uint4 u = *(const uint4*)(xg + (size_t)gi[c4][t] * 256);
          uint_t wsv[4] = {u.x, u.y, u.z, u.w};
#pragma unroll
          for (int q = 0; q < 4; ++q) {
            av[2 * q] += wgt * __uint_as_float(wsv[q] << 16);
            av[2 * q + 1] += wgt * __uint_as_float(wsv[q] & 0xffff0000u);
          }
        }
        uint4 o;
        o.x = pk2(av[0], av[1]); o.y = pk2(av[2], av[3]);
        o.z = pk2(av[4], av[5]); o.w = pk2(av[6], av[7]);
        *(uint4*)(&val[spx][(k << 5) + (sc8 << 3)]) = o;
      }
    }
    __syncthreads();
    // ---- GEMM: K=288 (9 chunks of 32), A=weights (global, L2-hot), B=val
    const ushort_t* wg = Wd + (size_t)(((g << 8) + cobase + (wv << 5))) * 288;
#pragma unroll
    for (int kc = 0; kc < 9; ++kc) {
      short8 af[2];
#pragma unroll
      for (int mi = 0; mi < 2; ++mi)
        af[mi] = *(const short8*)(wg + (size_t)((mi << 4) + r15) * 288 + (kc << 5) + (oct << 3));
#pragma unroll
      for (int ni = 0; ni < 4; ++ni) {
        short8 bfr = *(const short8*)(&val[(ni << 4) + r15][(kc << 5) + (oct << 3)]);
        acc[0][ni] = __builtin_amdgcn_mfma_f32_16x16x32_bf16(af[0], bfr, acc[0][ni], 0, 0, 0);
        acc[1][ni] = __builtin_amdgcn_mfma_f32_16x16x32_bf16(af[1], bfr, acc[1][ni], 0, 0, 0);
      }
    }
  }
  // ---- epilogue: fp32 NCHW coalesced
  const int coq = oct << 2;
#pragma unroll
  for (int mi = 0; mi < 2; ++mi) {
    int co4 = cobase + (wv << 5) + (mi << 4) + coq;
    float4 bv = *(const float4*)(bias + co4);
#pragma unroll
    for (int ni = 0; ni < 4; ++ni) {
      int px = (ni << 4) + r15;
      f32x4 a = acc[mi][ni];
      size_t e = (((size_t)b << 8) + co4) * 4096 + (y << 6) + px;
      out[e] = a[0] + bv.x;
      out[e + 4096] = a[1] + bv.y;
      out[e + 8192] = a[2] + bv.z;
      out[e + 12288] = a[3] + bv.w;
    }
  }
}

// ---------------------------------------------------------------------------
extern "C" void kernel_launch(void* const* d_in, const int* in_sizes, int n_in,
                              void* d_out, int out_size, void* d_ws,
                              size_t ws_size, hipStream_t stream) {
  const float* x_main = (const float*)d_in[0];
  const float* prior = (const float*)d_in[1];
  const float* w_ds = (const float*)d_in[2];
  const float* b_ds = (const float*)d_in[3];
  const float* w1 = (const float*)d_in[4];
  const float* b1 = (const float*)d_in[5];
  const float* g1 = (const float*)d_in[6];
  const float* bt1 = (const float*)d_in[7];
  const float* w_dw = (const float*)d_in[8];
  const float* b_dw = (const float*)d_in[9];
  const float* g2 = (const float*)d_in[10];
  const float* bt2 = (const float*)d_in[11];
  const float* w2 = (const float*)d_in[12];
  const float* b2 = (const float*)d_in[13];
  const float* w3 = (const float*)d_in[14];
  const float* b3 = (const float*)d_in[15];
  const float* g3 = (const float*)d_in[16];
  const float* bt3 = (const float*)d_in[17];
  const float* w_off = (const float*)d_in[18];
  const float* b_off = (const float*)d_in[19];
  const float* w_dcn = (const float*)d_in[20];
  const float* b_dcn = (const float*)d_in[21];

  float* out = (float*)d_out;
  float* warp = out;
  float* offf = out + 2097152;

  char* ws = (char*)d_ws;
  ushort_t* P1 = (ushort_t*)(ws + OFF_P1);
  ushort_t* Y1 = (ushort_t*)(ws + OFF_Y1);
  ushort_t* Y2 = (ushort_t*)(ws + OFF_Y2);
  ushort_t* o16 = (ushort_t*)(ws + OFF_O);
  ushort_t* Wds = (ushort_t*)(ws + OFF_WDS);
  ushort_t* W1 = (ushort_t*)(ws + OFF_W1);
  ushort_t* W2 = (ushort_t*)(ws + OFF_W2);
  ushort_t* W3 = (ushort_t*)(ws + OFF_W3);
  ushort_t* xb = (ushort_t*)(ws + OFF_X);
  float* Wdw = (float*)(ws + OFF_WDW);
  // after conv-w2, Y1 region is dead -> reuse for Wof + Wd
  ushort_t* Wof = Y1;
  ushort_t* Wd = Y1 + 589824;

  hipMemsetAsync(ws + OFF_P1, 0, 4460544, stream);
  k_wprep_all<<<5425, 256, 0, stream>>>(w_ds, w1, w2, w3, w_dw, Wds, W1, W2, W3, Wdw);
  // downsample prior -> Y2 (bf16 NCHW temp) -> padded NHWC P1
  k_down<<<8192, 256, 0, stream>>>(prior, Y2);
  k_tr<ushort_t><<<512, 256, 0, stream>>>(Y2, P1, 1);
  // x_main -> xb (NHWC bf16) — lives until DCN
  k_tr<float><<<512, 256, 0, stream>>>(x_main, xb, 0);
  // conv3x3 w_ds : P1 -> Y1
  k_convmfma<9, 256><<<dim3(128, 2), 256, 0, stream>>>(P1, nullptr, Wds, b_ds,
                                                       nullptr, Y1, nullptr, 256, 66, 66, 64, 0);
  // conv1x1 w1 : concat(Y1, xb) -> Y2
  k_convmfma<1, 512><<<dim3(128, 2), 256, 0, stream>>>(Y1, xb, W1, b1,
                                                       nullptr, Y2, nullptr, 256, 64, 64, 64, 0);
  // gn1+silu : Y2 -> Y1
  k_gn_nhwc<<<64, 256, 0, stream>>>(Y2, Y1, 64, 0, nullptr, g1, bt1);
  // dw7 : Y1 -> Y2
  k_dw7_nhwc<<<1024, 256, 0, stream>>>(Y1, Wdw, b_dw, Y2);
  // gn2+silu : Y2 -> Y1
  k_gn_nhwc<<<64, 256, 0, stream>>>(Y2, Y1, 64, 0, nullptr, g2, bt2);
  // conv1x1 w2 : Y1 -> P1 (padded)
  k_convmfma<1, 256><<<dim3(128, 2), 256, 0, stream>>>(Y1, nullptr, W2, b2,
                                                       nullptr, P1, nullptr, 256, 64, 64, 66, 1);
  // Y1 now dead: prep Wof + Wd into its region
  k_wprep_off<<<2304, 256, 0, stream>>>(w_off, Wof);
  k_wdcn<<<2304, 256, 0, stream>>>(w_dcn, Wd);
  // conv3x3 w3 : P1 -> Y2
  k_convmfma<9, 256><<<dim3(128, 2), 256, 0, stream>>>(P1, nullptr, W3, b3,
                                                       nullptr, Y2, nullptr, 256, 66, 66, 64, 0);
  // gn3+silu : Y2 -> {offset_feat fp32 NCHW, P1 padded}
  k_gn_nhwc<<<64, 256, 0, stream>>>(Y2, P1, 66, 1, offf, g3, bt3);
  // conv3x3 w_off : P1 -> o16 (bf16 NCHW, 216 ch)
  k_convmfma<9, 256><<<dim3(128, 2), 256, 0, stream>>>(P1, nullptr, Wof, b_off,
                                                       nullptr, nullptr, o16, 216, 66, 66, 64, 0);
  // DCN (bf16 MFMA)
  k_dcn_mfma<<<dim3(128, 2), 256, 0, stream>>>(xb, o16, Wd, b_dcn, warp);
}

// Round 4
// 373.461 us; speedup vs baseline: 4.8014x; 1.1224x over previous
//
#include <hip/hip_runtime.h>
#include <math.h>

// ---------------------------------------------------------------------------
// TextureWarpingModule  B=2, CH=CC=256, H=W=64, DG=8, K=9, GN=32 groups
// Round 4: occupancy fixes. Convs: 64-co tiles, grid 512 (2 blocks/CU).
// DCN: (b,y,xhalf) blocks, no duplicated sampling, conflict-free val writes.
// GN: stat+apply split, coalesced. gn3 NCHW-out via dedicated transpose.
// ---------------------------------------------------------------------------

typedef __attribute__((ext_vector_type(8))) short short8;   // 8 bf16 = 4 VGPR
typedef __attribute__((ext_vector_type(4))) float f32x4;
typedef unsigned short ushort_t;
typedef unsigned int uint_t;

__device__ __forceinline__ ushort_t f2bf(float f) {
  uint_t u = __float_as_uint(f);
  return (ushort_t)((u + 0x7fffu + ((u >> 16) & 1u)) >> 16);  // RNE
}
__device__ __forceinline__ float bf2f(ushort_t h) {
  return __uint_as_float(((uint_t)h) << 16);
}
__device__ __forceinline__ uint_t pk2(float a, float b) {
  return (uint_t)f2bf(a) | ((uint_t)f2bf(b) << 16);
}

#define GLL(g, l) \
  __builtin_amdgcn_global_load_lds((const __attribute__((address_space(1))) void*)(const void*)(g), \
                                   (__attribute__((address_space(3))) void*)(void*)(l), 16, 0, 0)
#define WAITVM(n) __builtin_amdgcn_s_waitcnt(0x0F70 | (n))
#define CFENCE() asm volatile("" ::: "memory")

// ---- ws layout (bytes) -----------------------------------------------------
#define OFF_P1   0u            // padded NHWC bf16 2x66x66x256  (4,460,544)
#define OFF_Y1   4460544u      // NHWC bf16 2x64x64x256 (4,194,304); later Wof/Wd
#define OFF_Y2   8654848u      // NHWC bf16 2x64x64x256 (also bf16-NCHW temp)
#define OFF_O    12849152u     // o bf16 NCHW 2x216x4096 (3,538,944)
#define OFF_WDS  16388096u     // [9][256][256] bf16
#define OFF_W1   17567744u     // [1][256][512] bf16
#define OFF_W2   17829888u     // [1][256][256] bf16
#define OFF_W3   17960960u     // [9][256][256] bf16
#define OFF_X    19140608u     // xb NHWC bf16 (4,194,304) — live until DCN
#define OFF_WDW  23334912u     // [49][256] f32 (50,176)
#define OFF_GNP  23385088u     // GN partials [2][64][32][2] f32 (32,768)
// end: 23,417,856

// ---------------------------------------------------------------------------
// 1) antialiased bilinear 2x downsample  (fp32 NCHW in -> bf16 NCHW out)
__global__ __launch_bounds__(256) void k_down(const float* __restrict__ pr,
                                              ushort_t* __restrict__ out) {
  int idx = blockIdx.x * 256 + threadIdx.x;  // 2*256*64*64
  int x = idx & 63, y = (idx >> 6) & 63, bc = idx >> 12;
  const float* p = pr + (size_t)bc * 16384;
  const float w4[4] = {0.125f, 0.375f, 0.375f, 0.125f};
  float wy[4], wx[4];
  int ry[4], rx[4];
  float sy = 0.f, sx = 0.f;
#pragma unroll
  for (int t = 0; t < 4; ++t) {
    int yy = 2 * y - 1 + t;
    bool vy = (yy >= 0) && (yy < 128);
    wy[t] = vy ? w4[t] : 0.f; ry[t] = vy ? yy : 0; sy += wy[t];
    int xx = 2 * x - 1 + t;
    bool vx = (xx >= 0) && (xx < 128);
    wx[t] = vx ? w4[t] : 0.f; rx[t] = vx ? xx : 0; sx += wx[t];
  }
  float acc = 0.f;
#pragma unroll
  for (int t = 0; t < 4; ++t) {
    const float* rowp = p + ry[t] * 128;
    acc += wy[t] * (wx[0] * rowp[rx[0]] + wx[1] * rowp[rx[1]] +
                    wx[2] * rowp[rx[2]] + wx[3] * rowp[rx[3]]);
  }
  out[idx] = f2bf(acc / (sy * sx));
}

// ---------------------------------------------------------------------------
// 2) NCHW -> NHWC transpose (+ optional 1px pad offset), bf16 out
template <typename SrcT>
__global__ __launch_bounds__(256) void k_tr(const SrcT* __restrict__ src,
                                            ushort_t* __restrict__ dst,
                                            int pad) {
  __shared__ SrcT tile[64][65];
  int bx = blockIdx.x;                // 2*64*4 = 512
  int c4 = bx & 3, y = (bx >> 2) & 63, b = bx >> 8;
  int tid = threadIdx.x;
  int x = tid & 63, cl = tid >> 6;
#pragma unroll
  for (int i = 0; i < 16; ++i) {
    int c = (c4 << 6) + cl + (i << 2);
    tile[cl + (i << 2)][x] = src[(((size_t)(b * 256 + c)) << 12) + (y << 6) + x];
  }
  __syncthreads();
  int W = 64 + 2 * pad;
  int c2 = tid & 63, xq = tid >> 6;
#pragma unroll
  for (int i = 0; i < 16; ++i) {
    int x2 = xq + (i << 2);
    SrcT v = tile[c2][x2];
    ushort_t o;
    if constexpr (sizeof(SrcT) == 4) o = f2bf((float)v); else o = (ushort_t)v;
    dst[((size_t)((b * W + y + pad) * W + x2 + pad)) * 256 + (c4 << 6) + c2] = o;
  }
}

// ---------------------------------------------------------------------------
// 2b) padded-NHWC bf16 -> NCHW fp32 (for offset_feat output)
__global__ __launch_bounds__(256) void k_trnf(const ushort_t* __restrict__ src,
                                              float* __restrict__ dst) {
  __shared__ float tile[64][65];
  int bx = blockIdx.x;                // 512 : b(1)|y(6)|cq(2)
  int cq = bx & 3, y = (bx >> 2) & 63, b = bx >> 8;
  int tid = threadIdx.x;
  int s8 = tid & 7, px = tid >> 3;    // 8 ch-slots x 32 px
#pragma unroll
  for (int i = 0; i < 2; ++i) {
    int p = px + (i << 5);
    uint4 u = *(const uint4*)(src + ((size_t)((b * 66 + y + 1) * 66 + p + 1)) * 256 + (cq << 6) + (s8 << 3));
    uint_t w[4] = {u.x, u.y, u.z, u.w};
#pragma unroll
    for (int q = 0; q < 4; ++q) {
      tile[(s8 << 3) + 2 * q][p] = __uint_as_float(w[q] << 16);
      tile[(s8 << 3) + 2 * q + 1][p] = __uint_as_float(w[q] & 0xffff0000u);
    }
  }
  __syncthreads();
  int x2 = tid & 63, cl = tid >> 6;
#pragma unroll
  for (int i = 0; i < 16; ++i) {
    int c = cl + (i << 2);
    dst[((size_t)(b * 256 + (cq << 6) + c)) * 4096 + (y << 6) + x2] = tile[c][x2];
  }
}

// ---------------------------------------------------------------------------
// 3) weight prep
__global__ __launch_bounds__(256) void k_wprep_all(
    const float* __restrict__ w_ds, const float* __restrict__ w1,
    const float* __restrict__ w2, const float* __restrict__ w3,
    const float* __restrict__ w_dw,
    ushort_t* __restrict__ Wds, ushort_t* __restrict__ W1,
    ushort_t* __restrict__ W2, ushort_t* __restrict__ W3,
    float* __restrict__ Wdw) {
  int i = blockIdx.x * 256 + threadIdx.x;  // 1,388,800
  if (i < 589824) {
    int tap = i >> 16, r = i & 65535, co = r >> 8, ci = r & 255;
    Wds[i] = f2bf(w_ds[((co << 8) + ci) * 9 + tap]);
  } else if (i < 720896) {
    int l = i - 589824;
    W1[l] = f2bf(w1[l]);
  } else if (i < 786432) {
    int l = i - 720896;
    W2[l] = f2bf(w2[l]);
  } else if (i < 1376256) {
    int l = i - 786432;
    int tap = l >> 16, r = l & 65535, co = r >> 8, ci = r & 255;
    W3[l] = f2bf(w3[((co << 8) + ci) * 9 + tap]);
  } else if (i < 1388800) {
    int l = i - 1376256;                 // 49*256
    int t = l >> 8, c = l & 255;
    Wdw[l] = w_dw[c * 49 + t];
  }
}

__global__ __launch_bounds__(256) void k_wprep_off(const float* __restrict__ w_off,
                                                   ushort_t* __restrict__ Wof) {
  int i = blockIdx.x * 256 + threadIdx.x;  // 589824
  int tap = i >> 16, r = i & 65535, co = r >> 8, ci = r & 255;
  Wof[i] = (co < 216) ? f2bf(w_off[((co << 8) + ci) * 9 + tap]) : (ushort_t)0;
}

// DCN weights: Wd[g][co][kk = k*32 + c] bf16 from w_dcn[co][ci=g*32+c][k]
__global__ __launch_bounds__(256) void k_wdcn(const float* __restrict__ w,
                                              ushort_t* __restrict__ Wd) {
  int i = blockIdx.x * 256 + threadIdx.x;  // 589824
  int kk = i % 288;
  int rest = i / 288;
  int co = rest & 255, g = rest >> 8;
  int k = kk >> 5, c = kk & 31;
  Wd[i] = f2bf(w[(size_t)co * 2304 + (g * 32 + c) * 9 + k]);
}

// ---------------------------------------------------------------------------
// 4) MFMA implicit-GEMM conv. 64-co tiles, grid (128, CEIL(CO/64)).
// 4 waves; wave = 16co x 64px, acc[4]. LDS 3 x (A4K + B4K) = 24KB.
template <int NTAPS, int CI>
__global__ __launch_bounds__(256) void k_convmfma(
    const ushort_t* __restrict__ srcA, const ushort_t* __restrict__ srcB,
    const ushort_t* __restrict__ wtp, const float* __restrict__ bias,
    float* __restrict__ outF,          // NCHW fp32 (or null)
    ushort_t* __restrict__ outB,       // NHWC bf16 (or null)
    ushort_t* __restrict__ outC16,     // NCHW bf16 (or null)
    int CO_real, int inH, int inW, int outW, int outPad) {
  const int gx = blockIdx.x;
  const int b = gx >> 6, y = gx & 63;
  const int cobase = blockIdx.y << 6;
  const int tid = threadIdx.x;
  const int wv = tid >> 6, lane = tid & 63;

  __shared__ __align__(16) char lds[24576];

  f32x4 acc[4];
#pragma unroll
  for (int ni = 0; ni < 4; ++ni) acc[ni] = (f32x4)0.f;

  const int sub = lane >> 2;                       // 0..15 rows per GLL
  const int oct = (lane & 3) ^ ((lane >> 3) & 3);  // source-swizzled ci-octet

  auto stage = [&](int s, int bufidx) {
    int tap, chunk;
    if constexpr (NTAPS == 9) { tap = s >> 3; chunk = s & 7; }
    else { tap = 0; chunk = s; }
    char* lb = lds + bufidx * 8192;
    {  // A (activations): wave stages px rows 16wv..16wv+15
      int px = (wv << 4) + sub;
      int srow, scol;
      if constexpr (NTAPS == 9) { srow = y + tap / 3; scol = tap % 3 + px; }
      else { srow = y; scol = px; }
      const ushort_t* sp = srcA;
      int cil = chunk << 5;
      if constexpr (CI == 512) {
        if (chunk >= 8) { sp = srcB; cil = (chunk & 7) << 5; }
      }
      const ushort_t* g = sp + ((size_t)((b * inH + srow) * inW + scol) * 256 + cil + (oct << 3));
      GLL(g, lb + (wv << 10));
    }
    {  // B (weights): wave stages co rows 16wv..16wv+15
      int col = (wv << 4) + sub;
      const ushort_t* g = wtp + ((size_t)(tap * 256 + cobase + col) * CI + (chunk << 5) + (oct << 3));
      GLL(g, lb + 4096 + (wv << 10));
    }
  };

  const int NSTEP = NTAPS * (CI >> 5);
  stage(0, 0);
  stage(1, 1);

  const int r15 = lane & 15;
  const int xo = (((lane >> 4) ^ ((lane >> 1) & 3)) << 4);

  for (int s = 0; s < NSTEP; ++s) {
    if (s + 2 < NSTEP) stage(s + 2, (s + 2) % 3);
    if (s + 2 < NSTEP) WAITVM(4);
    else if (s + 1 < NSTEP) WAITVM(2);
    else WAITVM(0);
    CFENCE();
    __builtin_amdgcn_s_barrier();
    CFENCE();
    char* lb = lds + (s % 3) * 8192;
    short8 af = *(const short8*)(lb + 4096 + (((wv << 4) + r15) << 6) + xo);
#pragma unroll
    for (int ni = 0; ni < 4; ++ni) {
      short8 bfr = *(const short8*)(lb + (((ni << 4) + r15) << 6) + xo);
      acc[ni] = __builtin_amdgcn_mfma_f32_16x16x32_bf16(af, bfr, acc[ni], 0, 0, 0);
    }
    CFENCE();
    __builtin_amdgcn_s_barrier();
    CFENCE();
  }

  const int coq = (lane >> 4) << 2;
  const int outH = 64 + 2 * outPad;
  int co4 = cobase + (wv << 4) + coq;
  if (co4 < CO_real) {
    float4 bv = *(const float4*)(bias + co4);
#pragma unroll
    for (int ni = 0; ni < 4; ++ni) {
      int px = (ni << 4) + r15;
      f32x4 a = acc[ni];
      if (outF) {
        size_t e = ((size_t)(b * CO_real + co4)) * 4096 + (y << 6) + px;
        outF[e] = a[0] + bv.x;
        outF[e + 4096] = a[1] + bv.y;
        outF[e + 8192] = a[2] + bv.z;
        outF[e + 12288] = a[3] + bv.w;
      }
      if (outC16) {
        size_t e = ((size_t)(b * CO_real + co4)) * 4096 + (y << 6) + px;
        outC16[e] = f2bf(a[0] + bv.x);
        outC16[e + 4096] = f2bf(a[1] + bv.y);
        outC16[e + 8192] = f2bf(a[2] + bv.z);
        outC16[e + 12288] = f2bf(a[3] + bv.w);
      }
      if (outB) {
        size_t e = ((size_t)((b * outH + y + outPad) * outW + px + outPad)) * 256 + co4;
        uint2 u;
        u.x = pk2(a[0] + bv.x, a[1] + bv.y);
        u.y = pk2(a[2] + bv.z, a[3] + bv.w);
        *(uint2*)(outB + e) = u;
      }
    }
  }
}

// ---------------------------------------------------------------------------
// 5) GroupNorm stats: one block per (b,y) row, coalesced; deterministic partials.
__global__ __launch_bounds__(256) void k_gnstat(const ushort_t* __restrict__ in,
                                                float* __restrict__ part) {
  int bg = blockIdx.x;  // 128 = b*64+y
  int tid = threadIdx.x;
  int slot = tid & 31, px0 = tid >> 5;
  const ushort_t* base = in + ((size_t)(bg << 6)) * 256 + (slot << 3);
  float s = 0.f, ss = 0.f;
#pragma unroll
  for (int i = 0; i < 8; ++i) {
    uint4 u = *(const uint4*)(base + (size_t)(px0 + (i << 3)) * 256);
    uint_t w[4] = {u.x, u.y, u.z, u.w};
#pragma unroll
    for (int q = 0; q < 4; ++q) {
      float f0 = __uint_as_float(w[q] << 16);
      float f1 = __uint_as_float(w[q] & 0xffff0000u);
      s += f0 + f1;
      ss += f0 * f0 + f1 * f1;
    }
  }
  s += __shfl_down(s, 32);
  ss += __shfl_down(ss, 32);
  __shared__ float ls[4][32][2];
  int wv = tid >> 6, lane = tid & 63;
  if (lane < 32) { ls[wv][lane][0] = s; ls[wv][lane][1] = ss; }
  __syncthreads();
  if (tid < 32) {
    float S = ls[0][tid][0] + ls[1][tid][0] + ls[2][tid][0] + ls[3][tid][0];
    float SS = ls[0][tid][1] + ls[1][tid][1] + ls[2][tid][1] + ls[3][tid][1];
    part[((size_t)bg * 32 + tid) * 2] = S;
    part[((size_t)bg * 32 + tid) * 2 + 1] = SS;
  }
}

// 5b) GN apply + SiLU (NHWC bf16 -> NHWC bf16, optional pad)
__global__ __launch_bounds__(256) void k_gnapply(const ushort_t* __restrict__ in,
                                                 const float* __restrict__ part,
                                                 const float* __restrict__ gamma,
                                                 const float* __restrict__ beta,
                                                 ushort_t* __restrict__ outN,
                                                 int outW, int outPad) {
  int bg = blockIdx.x;  // 128
  int b = bg >> 6, y = bg & 63;
  int tid = threadIdx.x;
  __shared__ float stats[32][2];
  if (tid < 64) {
    int slot = tid & 31, which = tid >> 5;
    float a = 0.f;
    for (int r = 0; r < 64; ++r)
      a += part[((size_t)(((b << 6) + r) * 32 + slot)) * 2 + which];
    stats[slot][which] = a;
  }
  __syncthreads();
  int slot = tid & 31, px0 = tid >> 5;
  float mu = stats[slot][0] * (1.f / 32768.f);
  float var = stats[slot][1] * (1.f / 32768.f) - mu * mu;
  float rstd = rsqrtf(var + 1e-6f);
  int c0 = slot << 3;
  float gm[8], bt[8];
#pragma unroll
  for (int j = 0; j < 8; ++j) { gm[j] = gamma[c0 + j]; bt[j] = beta[c0 + j]; }
  const ushort_t* base = in + ((size_t)(bg << 6)) * 256 + c0;
#pragma unroll
  for (int i = 0; i < 8; ++i) {
    int px = px0 + (i << 3);
    uint4 u = *(const uint4*)(base + (size_t)px * 256);
    uint_t w[4] = {u.x, u.y, u.z, u.w};
    float o8[8];
#pragma unroll
    for (int q = 0; q < 4; ++q) {
      float f0 = __uint_as_float(w[q] << 16);
      float f1 = __uint_as_float(w[q] & 0xffff0000u);
      float v0 = (f0 - mu) * rstd * gm[2 * q] + bt[2 * q];
      float v1 = (f1 - mu) * rstd * gm[2 * q + 1] + bt[2 * q + 1];
      o8[2 * q] = v0 / (1.f + expf(-v0));
      o8[2 * q + 1] = v1 / (1.f + expf(-v1));
    }
    size_t e = ((size_t)((b * (64 + 2 * outPad) + y + outPad) * outW + px + outPad)) * 256 + c0;
    uint4 o;
    o.x = pk2(o8[0], o8[1]); o.y = pk2(o8[2], o8[3]);
    o.z = pk2(o8[4], o8[5]); o.w = pk2(o8[6], o8[7]);
    *(uint4*)(outN + e) = o;
  }
}

// ---------------------------------------------------------------------------
// 6) depthwise 7x7 pad 3, NHWC bf16.
__global__ __launch_bounds__(256) void k_dw7_nhwc(const ushort_t* __restrict__ in,
                                                  const float* __restrict__ wdwT,
                                                  const float* __restrict__ bias,
                                                  ushort_t* __restrict__ out) {
  int tid = threadIdx.x;
  int oct = tid & 31, pxl = tid >> 5;
  int pxg = blockIdx.x * 8 + pxl;  // 8192
  int b = pxg >> 12, rem = pxg & 4095, y = rem >> 6, x = rem & 63;
  float a[8];
  float4 b0 = *(const float4*)(bias + (oct << 3));
  float4 b1 = *(const float4*)(bias + (oct << 3) + 4);
  a[0] = b0.x; a[1] = b0.y; a[2] = b0.z; a[3] = b0.w;
  a[4] = b1.x; a[5] = b1.y; a[6] = b1.z; a[7] = b1.w;
#pragma unroll
  for (int ky = 0; ky < 7; ++ky) {
    int yy = y + ky - 3;
    if ((unsigned)yy >= 64u) continue;
#pragma unroll
    for (int kx = 0; kx < 7; ++kx) {
      int xx = x + kx - 3;
      if ((unsigned)xx >= 64u) continue;
      int t = ky * 7 + kx;
      uint4 u = *(const uint4*)(in + ((size_t)((b << 12) + (yy << 6) + xx)) * 256 + (oct << 3));
      float4 w0 = *(const float4*)(wdwT + (t << 8) + (oct << 3));
      float4 w1 = *(const float4*)(wdwT + (t << 8) + (oct << 3) + 4);
      uint_t ws[4] = {u.x, u.y, u.z, u.w};
      float f[8];
#pragma unroll
      for (int q = 0; q < 4; ++q) {
        f[2 * q] = __uint_as_float(ws[q] << 16);
        f[2 * q + 1] = __uint_as_float(ws[q] & 0xffff0000u);
      }
      a[0] += f[0] * w0.x; a[1] += f[1] * w0.y; a[2] += f[2] * w0.z; a[3] += f[3] * w0.w;
      a[4] += f[4] * w1.x; a[5] += f[5] * w1.y; a[6] += f[6] * w1.z; a[7] += f[7] * w1.w;
    }
  }
  uint4 o;
  o.x = pk2(a[0], a[1]); o.y = pk2(a[2], a[3]);
  o.z = pk2(a[4], a[5]); o.w = pk2(a[6], a[7]);
  *(uint4*)(out + ((size_t)pxg) * 256 + (oct << 3)) = o;
}

// ---------------------------------------------------------------------------
// 7) deformable conv v2, bf16 MFMA.
// Block = (b, y, xhalf): 32 px x all 256 co. 4 waves: wave = 64co x 32px,
// acc[4][2]. Sampling de-duplicated; val writes conflict-free (stride 296).
__global__ __launch_bounds__(256) void k_dcn_mfma(
    const ushort_t* __restrict__ xb,   // NHWC bf16 [2][64][64][256]
    const ushort_t* __restrict__ o16,  // NCHW bf16 [2][216][4096]
    const ushort_t* __restrict__ Wd,   // [8][256][288] bf16, kk=k*32+c
    const float* __restrict__ bias,
    float* __restrict__ out) {         // NCHW fp32 [2][256][4096]
  const int blk = blockIdx.x;          // 256 : b(1)|y(6)|xh(1)
  const int b = blk >> 7;
  const int y = (blk >> 1) & 63;
  const int xh = blk & 1;
  const int tid = threadIdx.x;
  const int wv = tid >> 6, lane = tid & 63;
  const int r15 = lane & 15, oct = lane >> 4;

  __shared__ float gw[4][288];
  __shared__ int gi[4][288];
  __shared__ __align__(16) ushort_t val[32][296];  // stride 592B: write-conflict-free

  f32x4 acc[4][2];
#pragma unroll
  for (int mi = 0; mi < 4; ++mi)
#pragma unroll
    for (int ni = 0; ni < 2; ++ni) acc[mi][ni] = (f32x4)0.f;

  const int spx = tid & 31;
  const int sslot = (tid >> 5) & 3;
  const int skh = tid >> 7;
  const size_t obase = (size_t)b * 216 * 4096;
  const int pxy0 = (y << 6) + (xh << 5);

  for (int g = 0; g < 8; ++g) {
    __syncthreads();
    // ---- geometry: (k 0..8, px 0..31)
    for (int t = tid; t < 288; t += 256) {
      int k = t >> 5, px = t & 31;
      int pxy = pxy0 + px;
      float oy = bf2f(o16[obase + (size_t)(18 * g + 2 * k) * 4096 + pxy]);
      float ox = bf2f(o16[obase + (size_t)(18 * g + 2 * k + 1) * 4096 + pxy]);
      float mm = bf2f(o16[obase + (size_t)(144 + 9 * g + k) * 4096 + pxy]);
      float m = 1.f / (1.f + expf(-mm));
      float py = (float)(y + (k / 3) - 1) + oy;
      float pxf = (float)((xh << 5) + px + (k % 3) - 1) + ox;
      float y0f = floorf(py), x0f = floorf(pxf);
      float wy1 = py - y0f, wx1 = pxf - x0f;
      int y0 = (int)y0f, xi0 = (int)x0f;
      int y1 = y0 + 1, xi1 = xi0 + 1;
      float vy0 = (y0 >= 0 && y0 < 64) ? 1.f : 0.f;
      float vy1 = (y1 >= 0 && y1 < 64) ? 1.f : 0.f;
      float vx0 = (xi0 >= 0 && xi0 < 64) ? 1.f : 0.f;
      float vx1 = (xi1 >= 0 && xi1 < 64) ? 1.f : 0.f;
      int y0c = min(max(y0, 0), 63), y1c = min(max(y1, 0), 63);
      int x0c = min(max(xi0, 0), 63), x1c = min(max(xi1, 0), 63);
      float wy0 = 1.f - wy1, wx0 = 1.f - wx1;
      gw[0][t] = wy0 * wx0 * m * vy0 * vx0;
      gw[1][t] = wy0 * wx1 * m * vy0 * vx1;
      gw[2][t] = wy1 * wx0 * m * vy1 * vx0;
      gw[3][t] = wy1 * wx1 * m * vy1 * vx1;
      gi[0][t] = (y0c << 6) + x0c;
      gi[1][t] = (y0c << 6) + x1c;
      gi[2][t] = (y1c << 6) + x0c;
      gi[3][t] = (y1c << 6) + x1c;
    }
    __syncthreads();
    // ---- sampling: thread = (px, slot); taps split by parity
    {
      const ushort_t* xg = xb + (((size_t)b << 12) << 8) + (g << 5) + (sslot << 3);
      for (int k = skh; k < 9; k += 2) {
        int t = (k << 5) + spx;
        float av[8];
#pragma unroll
        for (int j = 0; j < 8; ++j) av[j] = 0.f;
#pragma unroll
        for (int c4 = 0; c4 < 4; ++c4) {
          float wgt = gw[c4][t];
          uint4 u = *(const uint4*)(xg + (size_t)gi[c4][t] * 256);
          uint_t wsv[4] = {u.x, u.y, u.z, u.w};
#pragma unroll
          for (int q = 0; q < 4; ++q) {
            av[2 * q] += wgt * __uint_as_float(wsv[q] << 16);
            av[2 * q + 1] += wgt * __uint_as_float(wsv[q] & 0xffff0000u);
          }
        }
        uint4 o;
        o.x = pk2(av[0], av[1]); o.y = pk2(av[2], av[3]);
        o.z = pk2(av[4], av[5]); o.w = pk2(av[6], av[7]);
        *(uint4*)(&val[spx][(k << 5) + (sslot << 3)]) = o;
      }
    }
    __syncthreads();
    // ---- GEMM: K=288, A=Wd (L2, prefetched), B=val
    const ushort_t* wg = Wd + ((size_t)((g << 8) + (wv << 6))) * 288;
    short8 afn[4];
#pragma unroll
    for (int mi = 0; mi < 4; ++mi)
      afn[mi] = *(const short8*)(wg + (size_t)((mi << 4) + r15) * 288 + (oct << 3));
#pragma unroll
    for (int kc = 0; kc < 9; ++kc) {
      short8 afc[4];
#pragma unroll
      for (int mi = 0; mi < 4; ++mi) afc[mi] = afn[mi];
      if (kc < 8) {
#pragma unroll
        for (int mi = 0; mi < 4; ++mi)
          afn[mi] = *(const short8*)(wg + (size_t)((mi << 4) + r15) * 288 + ((kc + 1) << 5) + (oct << 3));
      }
      short8 bf0 = *(const short8*)(&val[r15][(kc << 5) + (oct << 3)]);
      short8 bf1 = *(const short8*)(&val[16 + r15][(kc << 5) + (oct << 3)]);
#pragma unroll
      for (int mi = 0; mi < 4; ++mi) {
        acc[mi][0] = __builtin_amdgcn_mfma_f32_16x16x32_bf16(afc[mi], bf0, acc[mi][0], 0, 0, 0);
        acc[mi][1] = __builtin_amdgcn_mfma_f32_16x16x32_bf16(afc[mi], bf1, acc[mi][1], 0, 0, 0);
      }
    }
  }
  // ---- epilogue: fp32 NCHW coalesced
#pragma unroll
  for (int mi = 0; mi < 4; ++mi) {
    int co4 = (wv << 6) + (mi << 4) + (oct << 2);
    float4 bv = *(const float4*)(bias + co4);
#pragma unroll
    for (int ni = 0; ni < 2; ++ni) {
      int px = (xh << 5) + (ni << 4) + r15;
      f32x4 a = acc[mi][ni];
      size_t e = (((size_t)b << 8) + co4) * 4096 + (y << 6) + px;
      out[e] = a[0] + bv.x;
      out[e + 4096] = a[1] + bv.y;
      out[e + 8192] = a[2] + bv.z;
      out[e + 12288] = a[3] + bv.w;
    }
  }
}

// ---------------------------------------------------------------------------
extern "C" void kernel_launch(void* const* d_in, const int* in_sizes, int n_in,
                              void* d_out, int out_size, void* d_ws,
                              size_t ws_size, hipStream_t stream) {
  const float* x_main = (const float*)d_in[0];
  const float* prior = (const float*)d_in[1];
  const float* w_ds = (const float*)d_in[2];
  const float* b_ds = (const float*)d_in[3];
  const float* w1 = (const float*)d_in[4];
  const float* b1 = (const float*)d_in[5];
  const float* g1 = (const float*)d_in[6];
  const float* bt1 = (const float*)d_in[7];
  const float* w_dw = (const float*)d_in[8];
  const float* b_dw = (const float*)d_in[9];
  const float* g2 = (const float*)d_in[10];
  const float* bt2 = (const float*)d_in[11];
  const float* w2 = (const float*)d_in[12];
  const float* b2 = (const float*)d_in[13];
  const float* w3 = (const float*)d_in[14];
  const float* b3 = (const float*)d_in[15];
  const float* g3 = (const float*)d_in[16];
  const float* bt3 = (const float*)d_in[17];
  const float* w_off = (const float*)d_in[18];
  const float* b_off = (const float*)d_in[19];
  const float* w_dcn = (const float*)d_in[20];
  const float* b_dcn = (const float*)d_in[21];

  float* out = (float*)d_out;
  float* warp = out;
  float* offf = out + 2097152;

  char* ws = (char*)d_ws;
  ushort_t* P1 = (ushort_t*)(ws + OFF_P1);
  ushort_t* Y1 = (ushort_t*)(ws + OFF_Y1);
  ushort_t* Y2 = (ushort_t*)(ws + OFF_Y2);
  ushort_t* o16 = (ushort_t*)(ws + OFF_O);
  ushort_t* Wds = (ushort_t*)(ws + OFF_WDS);
  ushort_t* W1 = (ushort_t*)(ws + OFF_W1);
  ushort_t* W2 = (ushort_t*)(ws + OFF_W2);
  ushort_t* W3 = (ushort_t*)(ws + OFF_W3);
  ushort_t* xb = (ushort_t*)(ws + OFF_X);
  float* Wdw = (float*)(ws + OFF_WDW);
  float* gnp = (float*)(ws + OFF_GNP);
  ushort_t* Wof = Y1;                 // after conv-w2, Y1 region is dead
  ushort_t* Wd = Y1 + 589824;

  hipMemsetAsync(ws + OFF_P1, 0, 4460544, stream);
  k_wprep_all<<<5425, 256, 0, stream>>>(w_ds, w1, w2, w3, w_dw, Wds, W1, W2, W3, Wdw);
  k_down<<<8192, 256, 0, stream>>>(prior, Y2);
  k_tr<ushort_t><<<512, 256, 0, stream>>>(Y2, P1, 1);
  k_tr<float><<<512, 256, 0, stream>>>(x_main, xb, 0);
  // conv3x3 w_ds : P1 -> Y1
  k_convmfma<9, 256><<<dim3(128, 4), 256, 0, stream>>>(P1, nullptr, Wds, b_ds,
                                                       nullptr, Y1, nullptr, 256, 66, 66, 64, 0);
  // conv1x1 w1 : concat(Y1, xb) -> Y2
  k_convmfma<1, 512><<<dim3(128, 4), 256, 0, stream>>>(Y1, xb, W1, b1,
                                                       nullptr, Y2, nullptr, 256, 64, 64, 64, 0);
  // gn1+silu : Y2 -> Y1
  k_gnstat<<<128, 256, 0, stream>>>(Y2, gnp);
  k_gnapply<<<128, 256, 0, stream>>>(Y2, gnp, g1, bt1, Y1, 64, 0);
  // dw7 : Y1 -> Y2
  k_dw7_nhwc<<<1024, 256, 0, stream>>>(Y1, Wdw, b_dw, Y2);
  // gn2+silu : Y2 -> Y1
  k_gnstat<<<128, 256, 0, stream>>>(Y2, gnp);
  k_gnapply<<<128, 256, 0, stream>>>(Y2, gnp, g2, bt2, Y1, 64, 0);
  // conv1x1 w2 : Y1 -> P1 (padded)
  k_convmfma<1, 256><<<dim3(128, 4), 256, 0, stream>>>(Y1, nullptr, W2, b2,
                                                       nullptr, P1, nullptr, 256, 64, 64, 66, 1);
  // Y1 dead: prep Wof + Wd
  k_wprep_off<<<2304, 256, 0, stream>>>(w_off, Wof);
  k_wdcn<<<2304, 256, 0, stream>>>(w_dcn, Wd);
  // conv3x3 w3 : P1 -> Y2
  k_convmfma<9, 256><<<dim3(128, 4), 256, 0, stream>>>(P1, nullptr, W3, b3,
                                                       nullptr, Y2, nullptr, 256, 66, 66, 64, 0);
  // gn3+silu : Y2 -> P1 (padded)
  k_gnstat<<<128, 256, 0, stream>>>(Y2, gnp);
  k_gnapply<<<128, 256, 0, stream>>>(Y2, gnp, g3, bt3, P1, 66, 1);
  // offset_feat fp32 NCHW output
  k_trnf<<<512, 256, 0, stream>>>(P1, offf);
  // conv3x3 w_off : P1 -> o16 (bf16 NCHW, 216 ch)
  k_convmfma<9, 256><<<dim3(128, 4), 256, 0, stream>>>(P1, nullptr, Wof, b_off,
                                                       nullptr, nullptr, o16, 216, 66, 66, 64, 0);
  // DCN
  k_dcn_mfma<<<256, 256, 0, stream>>>(xb, o16, Wd, b_dcn, warp);
}

// Round 6
// 338.404 us; speedup vs baseline: 5.2988x; 1.1036x over previous
//
#include <hip/hip_runtime.h>
#include <math.h>

// ---------------------------------------------------------------------------
// TextureWarpingModule  B=2, CH=CC=256, H=W=64, DG=8, K=9, GN=32 groups
// Round 5b: compile fix (inline lane>>4). Conv K-step 128 (dbuf, XOR-swizzle),
// DCN grid x2 straight loads, GN-stat fused into conv epilogues.
// ---------------------------------------------------------------------------

typedef __attribute__((ext_vector_type(8))) short short8;   // 8 bf16 = 4 VGPR
typedef __attribute__((ext_vector_type(4))) float f32x4;
typedef unsigned short ushort_t;
typedef unsigned int uint_t;

__device__ __forceinline__ ushort_t f2bf(float f) {
  uint_t u = __float_as_uint(f);
  return (ushort_t)((u + 0x7fffu + ((u >> 16) & 1u)) >> 16);  // RNE
}
__device__ __forceinline__ float bf2f(ushort_t h) {
  return __uint_as_float(((uint_t)h) << 16);
}
__device__ __forceinline__ uint_t pk2(float a, float b) {
  return (uint_t)f2bf(a) | ((uint_t)f2bf(b) << 16);
}

#define GLL(g, l) \
  __builtin_amdgcn_global_load_lds((const __attribute__((address_space(1))) void*)(const void*)(g), \
                                   (__attribute__((address_space(3))) void*)(void*)(l), 16, 0, 0)
#define WAITVM(n) __builtin_amdgcn_s_waitcnt(0x0F70 | (n))
#define CFENCE() asm volatile("" ::: "memory")

// ---- ws layout (bytes) -----------------------------------------------------
#define OFF_P1   0u            // padded NHWC bf16 2x66x66x256  (4,460,544)
#define OFF_Y1   4460544u      // NHWC bf16 2x64x64x256 (4,194,304)
#define OFF_Y2   8654848u      // NHWC bf16 2x64x64x256
#define OFF_O    12849152u     // o bf16 NCHW 2x216x4096 (3,538,944)
#define OFF_WDS  16388096u     // [9][256][256] bf16 (1,179,648)
#define OFF_W1   17567744u     // [256][512] bf16 (262,144)
#define OFF_W2   17829888u     // [256][256] bf16 (131,072)
#define OFF_W3   17960960u     // [9][256][256] bf16 (1,179,648)
#define OFF_X    19140608u     // xb NHWC bf16 (4,194,304) — live until DCN
#define OFF_WDW  23334912u     // [49][256] f32 (50,176)
#define OFF_GNP  23385088u     // GN partials [128][32][2] f32 (32,768)
#define OFF_WOF  23417856u     // [9][256][256] bf16 (1,179,648)
#define OFF_WD   24597504u     // [8][256][288] bf16 (1,179,648)
// end: 25,777,152  (< 26.2MB proven)

// ---------------------------------------------------------------------------
// 1) antialiased bilinear 2x downsample, fp32 NCHW -> padded NHWC bf16 (P1)
__global__ __launch_bounds__(256) void k_down_nhwc(const float* __restrict__ pr,
                                                   ushort_t* __restrict__ dst) {
  int bx = blockIdx.x;                 // 512 : b(1)|y(6)|cq(2)
  int cq = bx & 3, y = (bx >> 2) & 63, b = bx >> 8;
  int tid = threadIdx.x;
  int px = tid & 63, sub = tid >> 6;   // 64 px x 4 ch-subtiles
  int c0 = (cq << 6) + (sub << 4);

  const float w4[4] = {0.125f, 0.375f, 0.375f, 0.125f};
  float wy[4], wx[4];
  int ry[4], rx[4];
  float sy = 0.f, sx = 0.f;
#pragma unroll
  for (int t = 0; t < 4; ++t) {
    int yy = 2 * y - 1 + t;
    bool vy = (yy >= 0) && (yy < 128);
    wy[t] = vy ? w4[t] : 0.f; ry[t] = vy ? yy : 0; sy += wy[t];
    int xx = 2 * px - 1 + t;
    bool vx = (xx >= 0) && (xx < 128);
    wx[t] = vx ? w4[t] : 0.f; rx[t] = vx ? xx : 0; sx += wx[t];
  }
  float rn = 1.f / (sy * sx);

  ushort_t o16[16];
#pragma unroll
  for (int i = 0; i < 16; ++i) {
    const float* p = pr + (size_t)(b * 256 + c0 + i) * 16384;
    float acc = 0.f;
#pragma unroll
    for (int t = 0; t < 4; ++t) {
      const float* rp = p + ry[t] * 128;
      acc += wy[t] * (wx[0] * rp[rx[0]] + wx[1] * rp[rx[1]] +
                      wx[2] * rp[rx[2]] + wx[3] * rp[rx[3]]);
    }
    o16[i] = f2bf(acc * rn);
  }
  ushort_t* d = dst + ((size_t)((b * 66 + y + 1) * 66 + px + 1)) * 256 + c0;
  *(uint4*)(d) = *(uint4*)(&o16[0]);
  *(uint4*)(d + 8) = *(uint4*)(&o16[8]);
}

// ---------------------------------------------------------------------------
// 2) NCHW fp32 -> NHWC bf16 transpose (xb)
__global__ __launch_bounds__(256) void k_trf(const float* __restrict__ src,
                                             ushort_t* __restrict__ dst) {
  __shared__ float tile[64][65];
  int bx = blockIdx.x;                // 512
  int c4 = bx & 3, y = (bx >> 2) & 63, b = bx >> 8;
  int tid = threadIdx.x;
  int x = tid & 63, cl = tid >> 6;
#pragma unroll
  for (int i = 0; i < 16; ++i) {
    int c = (c4 << 6) + cl + (i << 2);
    tile[cl + (i << 2)][x] = src[(((size_t)(b * 256 + c)) << 12) + (y << 6) + x];
  }
  __syncthreads();
  int c2 = tid & 63, xq = tid >> 6;
#pragma unroll
  for (int i = 0; i < 16; ++i) {
    int x2 = xq + (i << 2);
    dst[((size_t)((b * 64 + y) * 64 + x2)) * 256 + (c4 << 6) + c2] = f2bf(tile[c2][x2]);
  }
}

// ---------------------------------------------------------------------------
// 2b) padded-NHWC bf16 -> NCHW fp32 (offset_feat output)
__global__ __launch_bounds__(256) void k_trnf(const ushort_t* __restrict__ src,
                                              float* __restrict__ dst) {
  __shared__ float tile[64][65];
  int bx = blockIdx.x;                // 512 : b(1)|y(6)|cq(2)
  int cq = bx & 3, y = (bx >> 2) & 63, b = bx >> 8;
  int tid = threadIdx.x;
  int s8 = tid & 7, px = tid >> 3;    // 8 ch-slots x 32 px
#pragma unroll
  for (int i = 0; i < 2; ++i) {
    int p = px + (i << 5);
    uint4 u = *(const uint4*)(src + ((size_t)((b * 66 + y + 1) * 66 + p + 1)) * 256 + (cq << 6) + (s8 << 3));
    uint_t w[4] = {u.x, u.y, u.z, u.w};
#pragma unroll
    for (int q = 0; q < 4; ++q) {
      tile[(s8 << 3) + 2 * q][p] = __uint_as_float(w[q] << 16);
      tile[(s8 << 3) + 2 * q + 1][p] = __uint_as_float(w[q] & 0xffff0000u);
    }
  }
  __syncthreads();
  int x2 = tid & 63, cl = tid >> 6;
#pragma unroll
  for (int i = 0; i < 16; ++i) {
    int c = cl + (i << 2);
    dst[((size_t)(b * 256 + (cq << 6) + c)) * 4096 + (y << 6) + x2] = tile[c][x2];
  }
}

// ---------------------------------------------------------------------------
// 3) weight prep (single kernel): Wds/W1/W2/W3 bf16, WdwT f32, Wof, Wd
__global__ __launch_bounds__(256) void k_wprep_all(
    const float* __restrict__ w_ds, const float* __restrict__ w1,
    const float* __restrict__ w2, const float* __restrict__ w3,
    const float* __restrict__ w_dw, const float* __restrict__ w_off,
    const float* __restrict__ w_dcn,
    ushort_t* __restrict__ Wds, ushort_t* __restrict__ W1,
    ushort_t* __restrict__ W2, ushort_t* __restrict__ W3,
    float* __restrict__ Wdw, ushort_t* __restrict__ Wof,
    ushort_t* __restrict__ Wd) {
  int i = blockIdx.x * 256 + threadIdx.x;  // 2,568,448
  if (i < 589824) {
    int tap = i >> 16, r = i & 65535, co = r >> 8, ci = r & 255;
    Wds[i] = f2bf(w_ds[((co << 8) + ci) * 9 + tap]);
  } else if (i < 720896) {
    int l = i - 589824;
    W1[l] = f2bf(w1[l]);
  } else if (i < 786432) {
    int l = i - 720896;
    W2[l] = f2bf(w2[l]);
  } else if (i < 1376256) {
    int l = i - 786432;
    int tap = l >> 16, r = l & 65535, co = r >> 8, ci = r & 255;
    W3[l] = f2bf(w3[((co << 8) + ci) * 9 + tap]);
  } else if (i < 1388800) {
    int l = i - 1376256;                 // 49*256
    int t = l >> 8, c = l & 255;
    Wdw[l] = w_dw[c * 49 + t];
  } else if (i < 1978624) {
    int l = i - 1388800;
    int tap = l >> 16, r = l & 65535, co = r >> 8, ci = r & 255;
    Wof[l] = (co < 216) ? f2bf(w_off[((co << 8) + ci) * 9 + tap]) : (ushort_t)0;
  } else if (i < 2568448) {
    int l = i - 1978624;
    int kk = l % 288;
    int rest = l / 288;
    int co = rest & 255, g = rest >> 8;
    int k = kk >> 5, c = kk & 31;
    Wd[l] = f2bf(w_dcn[(size_t)co * 2304 + (g * 32 + c) * 9 + k]);
  }
}

// ---------------------------------------------------------------------------
// 4) MFMA implicit-GEMM conv. 64-co x 64-px tiles, K-step 128. Double-buffered
// 64KB LDS, XOR-unit swizzle. 4 waves; wave = 16co x 64px, 16 MFMA per step.
template <int NTAPS, int CI>
__global__ __launch_bounds__(256) void k_convmfma(
    const ushort_t* __restrict__ srcA, const ushort_t* __restrict__ srcB,
    const ushort_t* __restrict__ wtp, const float* __restrict__ bias,
    ushort_t* __restrict__ outB,       // NHWC bf16 (or null)
    ushort_t* __restrict__ outC16,     // NCHW bf16 (or null)
    float* __restrict__ gnp,           // GN partials (or null)
    int CO_real, int inH, int inW, int outW, int outPad) {
  const int gx = blockIdx.x;
  const int b = gx >> 6, y = gx & 63;
  const int cobase = blockIdx.y << 6;
  const int tid = threadIdx.x;
  const int wv = tid >> 6, lane = tid & 63;
  const int r15 = lane & 15, oct = lane >> 4;

  __shared__ __align__(16) char lds[2][32768];  // [buf][A 16K | B 16K]

  f32x4 acc[4];
#pragma unroll
  for (int ni = 0; ni < 4; ++ni) acc[ni] = (f32x4)0.f;

  auto stage = [&](int s, int buf) {
    int tap, ch;
    if constexpr (NTAPS == 9) { tap = s >> 1; ch = s & 1; }
    else { tap = 0; ch = s; }
    char* lb = lds[buf];
    // A: 16 GLLs total, 4 per wave. GLL j covers px rows 4j..4j+3.
#pragma unroll
    for (int q = 0; q < 4; ++q) {
      int j = (wv << 2) + q;
      int px = (j << 2) + (lane >> 4);
      int u_log = (lane & 15) ^ (px & 7);
      int srow, scol;
      if constexpr (NTAPS == 9) { srow = y + tap / 3; scol = px + tap % 3; }
      else { srow = y; scol = px; }
      const ushort_t* sp = srcA;
      int cil = ch << 7;
      if constexpr (CI == 512) {
        if (ch >= 2) { sp = srcB; cil = (ch - 2) << 7; }
      }
      const ushort_t* g = sp + ((size_t)((b * inH + srow) * inW + scol) * 256 + cil + (u_log << 3));
      GLL(g, lb + (j << 10));
    }
    // B (weights): GLL j covers co rows 4j..4j+3.
#pragma unroll
    for (int q = 0; q < 4; ++q) {
      int j = (wv << 2) + q;
      int col = (j << 2) + (lane >> 4);
      int u_log = (lane & 15) ^ (col & 7);
      const ushort_t* g = wtp + ((size_t)(tap * 256 + cobase + col) * CI + (ch << 7) + (u_log << 3));
      GLL(g, lb + 16384 + (j << 10));
    }
  };

  const int NSTEP = (NTAPS == 9) ? 18 : (CI >> 7);
  stage(0, 0);

  for (int s = 0; s < NSTEP; ++s) {
    if (s + 1 < NSTEP) stage(s + 1, (s + 1) & 1);
    if (s + 1 < NSTEP) WAITVM(8);
    else WAITVM(0);
    CFENCE();
    __builtin_amdgcn_s_barrier();
    CFENCE();
    const char* lb = lds[s & 1];
    __builtin_amdgcn_s_setprio(1);
#pragma unroll
    for (int kc = 0; kc < 4; ++kc) {
      int u_rd = (((kc << 2) + oct) ^ (r15 & 7)) << 4;
      short8 af = *(const short8*)(lb + 16384 + (((wv << 4) + r15) << 8) + u_rd);
#pragma unroll
      for (int ni = 0; ni < 4; ++ni) {
        short8 bfr = *(const short8*)(lb + (((ni << 4) + r15) << 8) + u_rd);
        acc[ni] = __builtin_amdgcn_mfma_f32_16x16x32_bf16(af, bfr, acc[ni], 0, 0, 0);
      }
    }
    __builtin_amdgcn_s_setprio(0);
    CFENCE();
    __builtin_amdgcn_s_barrier();
    CFENCE();
  }

  // epilogue
  const int coq = oct << 2;
  const int outH = 64 + 2 * outPad;
  int co4 = cobase + (wv << 4) + coq;
  float s_l = 0.f, ss_l = 0.f;
  if (co4 < CO_real) {
    float4 bv = *(const float4*)(bias + co4);
#pragma unroll
    for (int ni = 0; ni < 4; ++ni) {
      int px = (ni << 4) + r15;
      f32x4 a = acc[ni];
      float v0 = a[0] + bv.x, v1 = a[1] + bv.y, v2 = a[2] + bv.z, v3 = a[3] + bv.w;
      if (gnp) {
        s_l += v0 + v1 + v2 + v3;
        ss_l += v0 * v0 + v1 * v1 + v2 * v2 + v3 * v3;
      }
      if (outC16) {
        size_t e = ((size_t)(b * CO_real + co4)) * 4096 + (y << 6) + px;
        outC16[e] = f2bf(v0);
        outC16[e + 4096] = f2bf(v1);
        outC16[e + 8192] = f2bf(v2);
        outC16[e + 12288] = f2bf(v3);
      }
      if (outB) {
        size_t e = ((size_t)((b * outH + y + outPad) * outW + px + outPad)) * 256 + co4;
        uint2 u;
        u.x = pk2(v0, v1);
        u.y = pk2(v2, v3);
        *(uint2*)(outB + e) = u;
      }
    }
  }
  if (gnp) {
    // reduce (s_l, ss_l) over each 32-lane half (co-slot = 8 channels)
#pragma unroll
    for (int m = 1; m <= 16; m <<= 1) {
      s_l += __shfl_xor(s_l, m);
      ss_l += __shfl_xor(ss_l, m);
    }
    if ((lane & 31) == 0) {
      int slot = (cobase >> 3) + (wv << 1) + (lane >> 5);
      float* p = gnp + ((size_t)((b << 6) + y) * 32 + slot) * 2;
      p[0] = s_l;
      p[1] = ss_l;
    }
  }
}

// ---------------------------------------------------------------------------
// 5) GroupNorm stats (for gn2 only): one block per (b,y) row.
__global__ __launch_bounds__(256) void k_gnstat(const ushort_t* __restrict__ in,
                                                float* __restrict__ part) {
  int bg = blockIdx.x;  // 128
  int tid = threadIdx.x;
  int slot = tid & 31, px0 = tid >> 5;
  const ushort_t* base = in + ((size_t)(bg << 6)) * 256 + (slot << 3);
  float s = 0.f, ss = 0.f;
#pragma unroll
  for (int i = 0; i < 8; ++i) {
    uint4 u = *(const uint4*)(base + (size_t)(px0 + (i << 3)) * 256);
    uint_t w[4] = {u.x, u.y, u.z, u.w};
#pragma unroll
    for (int q = 0; q < 4; ++q) {
      float f0 = __uint_as_float(w[q] << 16);
      float f1 = __uint_as_float(w[q] & 0xffff0000u);
      s += f0 + f1;
      ss += f0 * f0 + f1 * f1;
    }
  }
  s += __shfl_down(s, 32);
  ss += __shfl_down(ss, 32);
  __shared__ float ls[4][32][2];
  int wv = tid >> 6, lane = tid & 63;
  if (lane < 32) { ls[wv][lane][0] = s; ls[wv][lane][1] = ss; }
  __syncthreads();
  if (tid < 32) {
    float S = ls[0][tid][0] + ls[1][tid][0] + ls[2][tid][0] + ls[3][tid][0];
    float SS = ls[0][tid][1] + ls[1][tid][1] + ls[2][tid][1] + ls[3][tid][1];
    part[((size_t)bg * 32 + tid) * 2] = S;
    part[((size_t)bg * 32 + tid) * 2 + 1] = SS;
  }
}

// 5b) GN apply + SiLU
__global__ __launch_bounds__(256) void k_gnapply(const ushort_t* __restrict__ in,
                                                 const float* __restrict__ part,
                                                 const float* __restrict__ gamma,
                                                 const float* __restrict__ beta,
                                                 ushort_t* __restrict__ outN,
                                                 int outW, int outPad) {
  int bg = blockIdx.x;  // 128
  int b = bg >> 6, y = bg & 63;
  int tid = threadIdx.x;
  __shared__ float stats[32][2];
  if (tid < 64) {
    int slot = tid & 31, which = tid >> 5;
    float a = 0.f;
    for (int r = 0; r < 64; ++r)
      a += part[((size_t)(((b << 6) + r) * 32 + slot)) * 2 + which];
    stats[slot][which] = a;
  }
  __syncthreads();
  int slot = tid & 31, px0 = tid >> 5;
  float mu = stats[slot][0] * (1.f / 32768.f);
  float var = stats[slot][1] * (1.f / 32768.f) - mu * mu;
  float rstd = rsqrtf(var + 1e-6f);
  int c0 = slot << 3;
  float gm[8], bt[8];
#pragma unroll
  for (int j = 0; j < 8; ++j) { gm[j] = gamma[c0 + j]; bt[j] = beta[c0 + j]; }
  const ushort_t* base = in + ((size_t)(bg << 6)) * 256 + c0;
#pragma unroll
  for (int i = 0; i < 8; ++i) {
    int px = px0 + (i << 3);
    uint4 u = *(const uint4*)(base + (size_t)px * 256);
    uint_t w[4] = {u.x, u.y, u.z, u.w};
    float o8[8];
#pragma unroll
    for (int q = 0; q < 4; ++q) {
      float f0 = __uint_as_float(w[q] << 16);
      float f1 = __uint_as_float(w[q] & 0xffff0000u);
      float v0 = (f0 - mu) * rstd * gm[2 * q] + bt[2 * q];
      float v1 = (f1 - mu) * rstd * gm[2 * q + 1] + bt[2 * q + 1];
      o8[2 * q] = v0 / (1.f + expf(-v0));
      o8[2 * q + 1] = v1 / (1.f + expf(-v1));
    }
    size_t e = ((size_t)((b * (64 + 2 * outPad) + y + outPad) * outW + px + outPad)) * 256 + c0;
    uint4 o;
    o.x = pk2(o8[0], o8[1]); o.y = pk2(o8[2], o8[3]);
    o.z = pk2(o8[4], o8[5]); o.w = pk2(o8[6], o8[7]);
    *(uint4*)(outN + e) = o;
  }
}

// ---------------------------------------------------------------------------
// 6) depthwise 7x7 pad 3, NHWC bf16.
__global__ __launch_bounds__(256) void k_dw7_nhwc(const ushort_t* __restrict__ in,
                                                  const float* __restrict__ wdwT,
                                                  const float* __restrict__ bias,
                                                  ushort_t* __restrict__ out) {
  int tid = threadIdx.x;
  int oct = tid & 31, pxl = tid >> 5;
  int pxg = blockIdx.x * 8 + pxl;  // 8192
  int b = pxg >> 12, rem = pxg & 4095, y = rem >> 6, x = rem & 63;
  float a[8];
  float4 b0 = *(const float4*)(bias + (oct << 3));
  float4 b1 = *(const float4*)(bias + (oct << 3) + 4);
  a[0] = b0.x; a[1] = b0.y; a[2] = b0.z; a[3] = b0.w;
  a[4] = b1.x; a[5] = b1.y; a[6] = b1.z; a[7] = b1.w;
#pragma unroll
  for (int ky = 0; ky < 7; ++ky) {
    int yy = y + ky - 3;
    if ((unsigned)yy >= 64u) continue;
#pragma unroll
    for (int kx = 0; kx < 7; ++kx) {
      int xx = x + kx - 3;
      if ((unsigned)xx >= 64u) continue;
      int t = ky * 7 + kx;
      uint4 u = *(const uint4*)(in + ((size_t)((b << 12) + (yy << 6) + xx)) * 256 + (oct << 3));
      float4 w0 = *(const float4*)(wdwT + (t << 8) + (oct << 3));
      float4 w1 = *(const float4*)(wdwT + (t << 8) + (oct << 3) + 4);
      uint_t ws[4] = {u.x, u.y, u.z, u.w};
      float f[8];
#pragma unroll
      for (int q = 0; q < 4; ++q) {
        f[2 * q] = __uint_as_float(ws[q] << 16);
        f[2 * q + 1] = __uint_as_float(ws[q] & 0xffff0000u);
      }
      a[0] += f[0] * w0.x; a[1] += f[1] * w0.y; a[2] += f[2] * w0.z; a[3] += f[3] * w0.w;
      a[4] += f[4] * w1.x; a[5] += f[5] * w1.y; a[6] += f[6] * w1.z; a[7] += f[7] * w1.w;
    }
  }
  uint4 o;
  o.x = pk2(a[0], a[1]); o.y = pk2(a[2], a[3]);
  o.z = pk2(a[4], a[5]); o.w = pk2(a[6], a[7]);
  *(uint4*)(out + ((size_t)pxg) * 256 + (oct << 3)) = o;
}

// ---------------------------------------------------------------------------
// 7) deformable conv v2, bf16 MFMA.
// Grid (256, 2): x = b|y|xhalf, y = co-half. Block: 32px x 128co, 4 waves,
// wave = 32co x 32px, acc[2][2]. Straight (hoistable) weight loads.
__global__ __launch_bounds__(256) void k_dcn_mfma(
    const ushort_t* __restrict__ xb,   // NHWC bf16 [2][64][64][256]
    const ushort_t* __restrict__ o16,  // NCHW bf16 [2][216][4096]
    const ushort_t* __restrict__ Wd,   // [8][256][288] bf16, kk=k*32+c
    const float* __restrict__ bias,
    float* __restrict__ out) {         // NCHW fp32 [2][256][4096]
  const int blk = blockIdx.x;          // 256 : b(1)|y(6)|xh(1)
  const int b = blk >> 7;
  const int y = (blk >> 1) & 63;
  const int xh = blk & 1;
  const int coh = blockIdx.y;          // 0/1
  const int tid = threadIdx.x;
  const int wv = tid >> 6, lane = tid & 63;
  const int r15 = lane & 15, oct = lane >> 4;

  __shared__ float gw[4][288];
  __shared__ int gi[4][288];
  __shared__ __align__(16) ushort_t val[32][296];

  f32x4 acc[2][2];
#pragma unroll
  for (int mi = 0; mi < 2; ++mi)
#pragma unroll
    for (int ni = 0; ni < 2; ++ni) acc[mi][ni] = (f32x4)0.f;

  const int spx = tid & 31;
  const int sslot = (tid >> 5) & 3;
  const int skh = tid >> 7;
  const size_t obase = (size_t)b * 216 * 4096;
  const int pxy0 = (y << 6) + (xh << 5);

  for (int g = 0; g < 8; ++g) {
    __syncthreads();
    // ---- geometry: (k 0..8, px 0..31)
    for (int t = tid; t < 288; t += 256) {
      int k = t >> 5, px = t & 31;
      int pxy = pxy0 + px;
      float oy = bf2f(o16[obase + (size_t)(18 * g + 2 * k) * 4096 + pxy]);
      float ox = bf2f(o16[obase + (size_t)(18 * g + 2 * k + 1) * 4096 + pxy]);
      float mm = bf2f(o16[obase + (size_t)(144 + 9 * g + k) * 4096 + pxy]);
      float m = 1.f / (1.f + expf(-mm));
      float py = (float)(y + (k / 3) - 1) + oy;
      float pxf = (float)((xh << 5) + px + (k % 3) - 1) + ox;
      float y0f = floorf(py), x0f = floorf(pxf);
      float wy1 = py - y0f, wx1 = pxf - x0f;
      int y0 = (int)y0f, xi0 = (int)x0f;
      int y1 = y0 + 1, xi1 = xi0 + 1;
      float vy0 = (y0 >= 0 && y0 < 64) ? 1.f : 0.f;
      float vy1 = (y1 >= 0 && y1 < 64) ? 1.f : 0.f;
      float vx0 = (xi0 >= 0 && xi0 < 64) ? 1.f : 0.f;
      float vx1 = (xi1 >= 0 && xi1 < 64) ? 1.f : 0.f;
      int y0c = min(max(y0, 0), 63), y1c = min(max(y1, 0), 63);
      int x0c = min(max(xi0, 0), 63), x1c = min(max(xi1, 0), 63);
      float wy0 = 1.f - wy1, wx0 = 1.f - wx1;
      gw[0][t] = wy0 * wx0 * m * vy0 * vx0;
      gw[1][t] = wy0 * wx1 * m * vy0 * vx1;
      gw[2][t] = wy1 * wx0 * m * vy1 * vx0;
      gw[3][t] = wy1 * wx1 * m * vy1 * vx1;
      gi[0][t] = (y0c << 6) + x0c;
      gi[1][t] = (y0c << 6) + x1c;
      gi[2][t] = (y1c << 6) + x0c;
      gi[3][t] = (y1c << 6) + x1c;
    }
    __syncthreads();
    // ---- sampling: thread = (px, slot, tap-parity)
    {
      const ushort_t* xg = xb + ((size_t)b << 20) + (g << 5) + (sslot << 3);
      for (int k = skh; k < 9; k += 2) {
        int t = (k << 5) + spx;
        float av[8];
#pragma unroll
        for (int j = 0; j < 8; ++j) av[j] = 0.f;
#pragma unroll
        for (int c4 = 0; c4 < 4; ++c4) {
          float wgt = gw[c4][t];
          uint4 u = *(const uint4*)(xg + (size_t)gi[c4][t] * 256);
          uint_t wsv[4] = {u.x, u.y, u.z, u.w};
#pragma unroll
          for (int q = 0; q < 4; ++q) {
            av[2 * q] += wgt * __uint_as_float(wsv[q] << 16);
            av[2 * q + 1] += wgt * __uint_as_float(wsv[q] & 0xffff0000u);
          }
        }
        uint4 o;
        o.x = pk2(av[0], av[1]); o.y = pk2(av[2], av[3]);
        o.z = pk2(av[4], av[5]); o.w = pk2(av[6], av[7]);
        *(uint4*)(&val[spx][(k << 5) + (sslot << 3)]) = o;
      }
    }
    __syncthreads();
    // ---- GEMM: K=288, straight loads (compiler hoists across unrolled kc)
    const ushort_t* wg = Wd + ((size_t)((g << 8) + (coh << 7) + (wv << 5))) * 288;
    __builtin_amdgcn_s_setprio(1);
#pragma unroll
    for (int kc = 0; kc < 9; ++kc) {
      short8 af0 = *(const short8*)(wg + (size_t)r15 * 288 + (kc << 5) + (oct << 3));
      short8 af1 = *(const short8*)(wg + (size_t)(16 + r15) * 288 + (kc << 5) + (oct << 3));
      short8 bf0 = *(const short8*)(&val[r15][(kc << 5) + (oct << 3)]);
      short8 bf1 = *(const short8*)(&val[16 + r15][(kc << 5) + (oct << 3)]);
      acc[0][0] = __builtin_amdgcn_mfma_f32_16x16x32_bf16(af0, bf0, acc[0][0], 0, 0, 0);
      acc[0][1] = __builtin_amdgcn_mfma_f32_16x16x32_bf16(af0, bf1, acc[0][1], 0, 0, 0);
      acc[1][0] = __builtin_amdgcn_mfma_f32_16x16x32_bf16(af1, bf0, acc[1][0], 0, 0, 0);
      acc[1][1] = __builtin_amdgcn_mfma_f32_16x16x32_bf16(af1, bf1, acc[1][1], 0, 0, 0);
    }
    __builtin_amdgcn_s_setprio(0);
  }
  // ---- epilogue: fp32 NCHW coalesced
#pragma unroll
  for (int mi = 0; mi < 2; ++mi) {
    int co4 = (coh << 7) + (wv << 5) + (mi << 4) + (oct << 2);
    float4 bv = *(const float4*)(bias + co4);
#pragma unroll
    for (int ni = 0; ni < 2; ++ni) {
      int px = (xh << 5) + (ni << 4) + r15;
      f32x4 a = acc[mi][ni];
      size_t e = (((size_t)b << 8) + co4) * 4096 + (y << 6) + px;
      out[e] = a[0] + bv.x;
      out[e + 4096] = a[1] + bv.y;
      out[e + 8192] = a[2] + bv.z;
      out[e + 12288] = a[3] + bv.w;
    }
  }
}

// ---------------------------------------------------------------------------
extern "C" void kernel_launch(void* const* d_in, const int* in_sizes, int n_in,
                              void* d_out, int out_size, void* d_ws,
                              size_t ws_size, hipStream_t stream) {
  const float* x_main = (const float*)d_in[0];
  const float* prior = (const float*)d_in[1];
  const float* w_ds = (const float*)d_in[2];
  const float* b_ds = (const float*)d_in[3];
  const float* w1 = (const float*)d_in[4];
  const float* b1 = (const float*)d_in[5];
  const float* g1 = (const float*)d_in[6];
  const float* bt1 = (const float*)d_in[7];
  const float* w_dw = (const float*)d_in[8];
  const float* b_dw = (const float*)d_in[9];
  const float* g2 = (const float*)d_in[10];
  const float* bt2 = (const float*)d_in[11];
  const float* w2 = (const float*)d_in[12];
  const float* b2 = (const float*)d_in[13];
  const float* w3 = (const float*)d_in[14];
  const float* b3 = (const float*)d_in[15];
  const float* g3 = (const float*)d_in[16];
  const float* bt3 = (const float*)d_in[17];
  const float* w_off = (const float*)d_in[18];
  const float* b_off = (const float*)d_in[19];
  const float* w_dcn = (const float*)d_in[20];
  const float* b_dcn = (const float*)d_in[21];

  float* out = (float*)d_out;
  float* warp = out;
  float* offf = out + 2097152;

  char* ws = (char*)d_ws;
  ushort_t* P1 = (ushort_t*)(ws + OFF_P1);
  ushort_t* Y1 = (ushort_t*)(ws + OFF_Y1);
  ushort_t* Y2 = (ushort_t*)(ws + OFF_Y2);
  ushort_t* o16 = (ushort_t*)(ws + OFF_O);
  ushort_t* Wds = (ushort_t*)(ws + OFF_WDS);
  ushort_t* W1 = (ushort_t*)(ws + OFF_W1);
  ushort_t* W2 = (ushort_t*)(ws + OFF_W2);
  ushort_t* W3 = (ushort_t*)(ws + OFF_W3);
  ushort_t* xb = (ushort_t*)(ws + OFF_X);
  float* Wdw = (float*)(ws + OFF_WDW);
  float* gnp = (float*)(ws + OFF_GNP);
  ushort_t* Wof = (ushort_t*)(ws + OFF_WOF);
  ushort_t* Wd = (ushort_t*)(ws + OFF_WD);

  (void)hipMemsetAsync(ws + OFF_P1, 0, 4460544, stream);
  k_wprep_all<<<10033, 256, 0, stream>>>(w_ds, w1, w2, w3, w_dw, w_off, w_dcn,
                                         Wds, W1, W2, W3, Wdw, Wof, Wd);
  // downsample prior -> padded NHWC P1 (direct)
  k_down_nhwc<<<512, 256, 0, stream>>>(prior, P1);
  // x_main -> xb (NHWC bf16)
  k_trf<<<512, 256, 0, stream>>>(x_main, xb);
  // conv3x3 w_ds : P1 -> Y1
  k_convmfma<9, 256><<<dim3(128, 4), 256, 0, stream>>>(P1, nullptr, Wds, b_ds,
                                                       Y1, nullptr, nullptr, 256, 66, 66, 64, 0);
  // conv1x1 w1 : concat(Y1, xb) -> Y2  (+ gn1 stats)
  k_convmfma<1, 512><<<dim3(128, 4), 256, 0, stream>>>(Y1, xb, W1, b1,
                                                       Y2, nullptr, gnp, 256, 64, 64, 64, 0);
  // gn1 apply : Y2 -> Y1
  k_gnapply<<<128, 256, 0, stream>>>(Y2, gnp, g1, bt1, Y1, 64, 0);
  // dw7 : Y1 -> Y2
  k_dw7_nhwc<<<1024, 256, 0, stream>>>(Y1, Wdw, b_dw, Y2);
  // gn2 : Y2 -> Y1
  k_gnstat<<<128, 256, 0, stream>>>(Y2, gnp);
  k_gnapply<<<128, 256, 0, stream>>>(Y2, gnp, g2, bt2, Y1, 64, 0);
  // conv1x1 w2 : Y1 -> P1 (padded)
  k_convmfma<1, 256><<<dim3(128, 4), 256, 0, stream>>>(Y1, nullptr, W2, b2,
                                                       P1, nullptr, nullptr, 256, 64, 64, 66, 1);
  // conv3x3 w3 : P1 -> Y2  (+ gn3 stats)
  k_convmfma<9, 256><<<dim3(128, 4), 256, 0, stream>>>(P1, nullptr, W3, b3,
                                                       Y2, nullptr, gnp, 256, 66, 66, 64, 0);
  // gn3 apply : Y2 -> P1 (padded)
  k_gnapply<<<128, 256, 0, stream>>>(Y2, gnp, g3, bt3, P1, 66, 1);
  // offset_feat fp32 NCHW output
  k_trnf<<<512, 256, 0, stream>>>(P1, offf);
  // conv3x3 w_off : P1 -> o16 (bf16 NCHW, 216 ch)
  k_convmfma<9, 256><<<dim3(128, 4), 256, 0, stream>>>(P1, nullptr, Wof, b_off,
                                                       nullptr, o16, nullptr, 216, 66, 66, 64, 0);
  // DCN
  k_dcn_mfma<<<dim3(256, 2), 256, 0, stream>>>(xb, o16, Wd, b_dcn, warp);
}